// Round 1
// baseline (27016.278 us; speedup 1.0000x reference)
//
#include <hip/hip_runtime.h>
#include <math.h>

// ---------------------------------------------------------------------------
// TCCL model forward: 3-stage conv encoder + template head + similarities.
// Round 0: correctness-first fp32 implementation.
// Strategy per conv+BN stage (training-mode BN needs batch stats of conv out):
//   K1: conv (recompute-friendly) + deterministic chunked per-channel
//       sum/sumsq partials                                  (no atomics)
//   K2: finalize -> scale/shift  (BN folds to scale*y+shift)
//   K3: recompute conv, apply BN+ReLU(+maxpool4), write pooled activation
// This avoids materializing the 134 MB stage-1 conv output entirely.
// ---------------------------------------------------------------------------

#define BSZ 256       // batch
#define NTHR 256      // threads per block (4 waves)

static inline int ceil_divll(long long a, int b) { return (int)((a + b - 1) / b); }

// conv + per-channel partial stats. grid = (Cout, nchunk), block = NTHR.
__global__ void conv_stats_kernel(const float* __restrict__ x, const float* __restrict__ wgt,
                                  const float* __restrict__ bias, float* __restrict__ partials,
                                  int Cin, int W, int K, int pad, int nchunk)
{
    const int co = blockIdx.x;
    const int chunk = blockIdx.y;
    const long long N = (long long)BSZ * W;
    const float* wbase = wgt + (long long)co * Cin * K;
    const float bi = bias[co];
    float s = 0.f, ss = 0.f;
    for (long long idx = (long long)chunk * NTHR + threadIdx.x; idx < N;
         idx += (long long)nchunk * NTHR) {
        const int b = (int)(idx / W);
        const int w = (int)(idx % W);
        float y = bi;
        const int t0 = max(0, pad - w);
        const int t1 = min(K, W + pad - w);
        for (int ci = 0; ci < Cin; ++ci) {
            const float* xp = x + ((long long)b * Cin + ci) * W + (w - pad);
            const float* wp = wbase + ci * K;
            for (int t = t0; t < t1; ++t) y += xp[t] * wp[t];
        }
        s += y; ss += y * y;
    }
    __shared__ float red[2 * NTHR];
    red[threadIdx.x] = s;
    red[threadIdx.x + NTHR] = ss;
    __syncthreads();
    for (int off = NTHR / 2; off > 0; off >>= 1) {
        if ((int)threadIdx.x < off) {
            red[threadIdx.x] += red[threadIdx.x + off];
            red[threadIdx.x + NTHR] += red[threadIdx.x + NTHR + off];
        }
        __syncthreads();
    }
    if (threadIdx.x == 0) {
        partials[((long long)co * nchunk + chunk) * 2 + 0] = red[0];
        partials[((long long)co * nchunk + chunk) * 2 + 1] = red[NTHR];
    }
}

// finalize: scale/shift per channel. grid=1, block=64.
__global__ void stats_finalize_kernel(const float* __restrict__ partials, int nchunk, float invN,
                                      const float* __restrict__ g, const float* __restrict__ be,
                                      float* __restrict__ scale, float* __restrict__ shift, int Cout)
{
    int co = blockIdx.x * blockDim.x + threadIdx.x;
    if (co >= Cout) return;
    float s = 0.f, ss = 0.f;
    for (int c = 0; c < nchunk; ++c) {
        s  += partials[(co * nchunk + c) * 2 + 0];
        ss += partials[(co * nchunk + c) * 2 + 1];
    }
    float m = s * invN;
    float v = ss * invN - m * m;
    float inv = rsqrtf(v + 1e-5f);
    float sc = g[co] * inv;
    scale[co] = sc;
    shift[co] = be[co] - sc * m;
}

// recompute conv, BN+ReLU+maxpool4. out: (B, Cout, W/4)
__global__ void conv_bn_pool_kernel(const float* __restrict__ x, const float* __restrict__ wgt,
                                    const float* __restrict__ bias,
                                    const float* __restrict__ scale, const float* __restrict__ shift,
                                    float* __restrict__ out,
                                    int Cin, int W, int K, int pad, int Cout)
{
    const int Wp = W >> 2;
    const long long total = (long long)BSZ * Cout * Wp;
    for (long long i = (long long)blockIdx.x * NTHR + threadIdx.x; i < total;
         i += (long long)gridDim.x * NTHR) {
        const int wp = (int)(i % Wp);
        const long long r = i / Wp;
        const int co = (int)(r % Cout);
        const int b = (int)(r / Cout);
        const float sc = scale[co], sh = shift[co], bi = bias[co];
        const float* wbase = wgt + (long long)co * Cin * K;
        float mx = 0.f;  // relu folds into max (all pooled values >= 0)
        for (int q = 0; q < 4; ++q) {
            const int w = (wp << 2) + q;
            const int t0 = max(0, pad - w);
            const int t1 = min(K, W + pad - w);
            float y = bi;
            for (int ci = 0; ci < Cin; ++ci) {
                const float* xp = x + ((long long)b * Cin + ci) * W + (w - pad);
                const float* wpp = wbase + ci * K;
                for (int t = t0; t < t1; ++t) y += xp[t] * wpp[t];
            }
            mx = fmaxf(mx, sc * y + sh);
        }
        out[i] = mx;
    }
}

// recompute conv, BN+ReLU (no pool). out: (B, Cout, W)
__global__ void conv_bn_relu_kernel(const float* __restrict__ x, const float* __restrict__ wgt,
                                    const float* __restrict__ bias,
                                    const float* __restrict__ scale, const float* __restrict__ shift,
                                    float* __restrict__ out,
                                    int Cin, int W, int K, int pad, int Cout)
{
    const long long total = (long long)BSZ * Cout * W;
    for (long long i = (long long)blockIdx.x * NTHR + threadIdx.x; i < total;
         i += (long long)gridDim.x * NTHR) {
        const int w = (int)(i % W);
        const long long r = i / W;
        const int co = (int)(r % Cout);
        const int b = (int)(r / Cout);
        const float sc = scale[co], sh = shift[co], bi = bias[co];
        const float* wbase = wgt + (long long)co * Cin * K;
        const int t0 = max(0, pad - w);
        const int t1 = min(K, W + pad - w);
        float y = bi;
        for (int ci = 0; ci < Cin; ++ci) {
            const float* xp = x + ((long long)b * Cin + ci) * W + (w - pad);
            const float* wpp = wbase + ci * K;
            for (int t = t0; t < t1; ++t) y += xp[t] * wpp[t];
        }
        out[i] = fmaxf(sc * y + sh, 0.f);
    }
}

// adaptive avg pool to K5 bins (torch bin boundaries). in: (B,C,W) out: (B,C,K5)
__global__ void adapool_kernel(const float* __restrict__ in, float* __restrict__ out,
                               int C, int W, int K5)
{
    const long long total = (long long)BSZ * C * K5;
    for (long long i = (long long)blockIdx.x * NTHR + threadIdx.x; i < total;
         i += (long long)gridDim.x * NTHR) {
        const int kk = (int)(i % K5);
        const long long r = i / K5;
        const int c = (int)(r % C);
        const int b = (int)(r / C);
        const int s = (kk * W) / K5;
        const int e = ((kk + 1) * W + K5 - 1) / K5;
        const float* p = in + ((long long)b * C + c) * W;
        float acc = 0.f;
        for (int w = s; w < e; ++w) acc += p[w];
        out[i] = acc / (float)(e - s);
    }
}

// center + l2-normalize each (b,c) row of 5. one thread per row.
__global__ void knorm_kernel(const float* __restrict__ k, float* __restrict__ kn, int nrows)
{
    int i = blockIdx.x * NTHR + threadIdx.x;
    if (i >= nrows) return;
    const float* p = k + (long long)i * 5;
    float m = 0.f;
    for (int t = 0; t < 5; ++t) m += p[t];
    m *= 0.2f;
    float v[5]; float n2 = 0.f;
    for (int t = 0; t < 5; ++t) { v[t] = p[t] - m; n2 += v[t] * v[t]; }
    float n = fmaxf(sqrtf(n2), 1e-12f);
    for (int t = 0; t < 5; ++t) kn[(long long)i * 5 + t] = v[t] / n;
}

// center+normalize each (b,c) row of h (W=128), emit the 5 window sums.
// With sum(hn)==0: S = {-(h[W-2]+h[W-1]), -h[W-1], 0, -h[0], -(h[0]+h[1])}
__global__ void srow_kernel(const float* __restrict__ h, float* __restrict__ S, int nrows, int W)
{
    int i = blockIdx.x * NTHR + threadIdx.x;
    if (i >= nrows) return;
    const float* p = h + (long long)i * W;
    float m = 0.f;
    for (int w = 0; w < W; ++w) m += p[w];
    m /= (float)W;
    float n2 = 0.f;
    for (int w = 0; w < W; ++w) { float d = p[w] - m; n2 += d * d; }
    float n = fmaxf(sqrtf(n2), 1e-12f);
    float h0 = (p[0] - m) / n, h1 = (p[1] - m) / n;
    float hN1 = (p[W - 1] - m) / n, hN2 = (p[W - 2] - m) / n;
    float* o = S + (long long)i * 5;
    o[0] = -(hN2 + hN1);
    o[1] = -hN1;
    o[2] = 0.f;
    o[3] = -h0;
    o[4] = -(h0 + h1);
}

// l2-normalize flattened rows of length D (no centering). one thread per row.
__global__ void flatnorm_kernel(const float* __restrict__ k, float* __restrict__ out, int nrows, int D)
{
    int i = blockIdx.x * NTHR + threadIdx.x;
    if (i >= nrows) return;
    const float* p = k + (long long)i * D;
    float n2 = 0.f;
    for (int d = 0; d < D; ++d) n2 += p[d] * p[d];
    float n = fmaxf(sqrtf(n2), 1e-12f);
    float* o = out + (long long)i * D;
    for (int d = 0; d < D; ++d) o[d] = p[d] / n;
}

// out[i][j] = coef * dot(A[i], B[j]) over D.  grid=(1, n), block=n<=NTHR
__global__ void simdot_kernel(const float* __restrict__ A, const float* __restrict__ Bm,
                              float* __restrict__ out, int n, int D, float coef)
{
    int j = blockIdx.x * NTHR + threadIdx.x;
    int i = blockIdx.y;
    if (j >= n) return;
    const float* a = A + (long long)i * D;
    const float* b = Bm + (long long)j * D;
    float acc = 0.f;
    for (int d = 0; d < D; ++d) acc += a[d] * b[d];
    out[(long long)i * n + j] = acc * coef;
}

// -mean_i log_softmax(sim*invT)[i,i].  single block of NTHR (n<=NTHR).
__global__ void infonce_kernel(const float* __restrict__ sim, int n, float invT,
                               float* __restrict__ loss)
{
    int i = threadIdx.x;
    float lp = 0.f;
    if (i < n) {
        const float* row = sim + (long long)i * n;
        float mx = -INFINITY;
        for (int j = 0; j < n; ++j) mx = fmaxf(mx, row[j] * invT);
        float se = 0.f;
        for (int j = 0; j < n; ++j) se += expf(row[j] * invT - mx);
        float lse = mx + logf(se);
        lp = row[i] * invT - lse;
    }
    __shared__ float red[NTHR];
    red[threadIdx.x] = (i < n) ? lp : 0.f;
    __syncthreads();
    for (int off = NTHR / 2; off > 0; off >>= 1) {
        if ((int)threadIdx.x < off) red[threadIdx.x] += red[threadIdx.x + off];
        __syncthreads();
    }
    if (threadIdx.x == 0) *loss = -red[0] / (float)n;
}

__global__ void final_kernel(const float* __restrict__ l, float* __restrict__ out)
{
    out[0] = 0.5f * (l[0] + l[1]) + 0.5f * l[2];
}

// ---------------------------------------------------------------------------

extern "C" void kernel_launch(void* const* d_in, const int* in_sizes, int n_in,
                              void* d_out, int out_size, void* d_ws, size_t ws_size,
                              hipStream_t stream)
{
    const float* x1  = (const float*)d_in[0];
    const float* x2  = (const float*)d_in[1];
    const float* w1  = (const float*)d_in[2];
    const float* b1  = (const float*)d_in[3];
    const float* g1  = (const float*)d_in[4];
    const float* be1 = (const float*)d_in[5];
    const float* w2  = (const float*)d_in[6];
    const float* b2  = (const float*)d_in[7];
    const float* g2  = (const float*)d_in[8];
    const float* be2 = (const float*)d_in[9];
    const float* w3  = (const float*)d_in[10];
    const float* b3  = (const float*)d_in[11];
    const float* g3  = (const float*)d_in[12];
    const float* be3 = (const float*)d_in[13];
    const float* tw1 = (const float*)d_in[14];
    const float* tb1 = (const float*)d_in[15];
    const float* tg1 = (const float*)d_in[16];
    const float* tbe1= (const float*)d_in[17];
    const float* tw2 = (const float*)d_in[18];
    const float* tb2 = (const float*)d_in[19];
    const float* tg2 = (const float*)d_in[20];
    const float* tbe2= (const float*)d_in[21];
    float* out = (float*)d_out;

    // workspace carve-up
    char* ws = (char*)d_ws;
    size_t off = 0;
    auto alloc = [&](size_t bytes) -> void* {
        off = (off + 255) & ~(size_t)255;
        void* p = ws + off;
        off += bytes;
        return p;
    };
    const int C = 64;
    float* h1f  = (float*)alloc((size_t)BSZ * C * 128 * 4);    // 8.4 MB
    float* h2f  = (float*)alloc((size_t)BSZ * C * 128 * 4);    // 8.4 MB
    float* act0 = (float*)alloc((size_t)BSZ * 16 * 2048 * 4);  // 33.6 MB (max act)
    float* act1 = (float*)alloc((size_t)BSZ * 32 * 512 * 4);   // 16.8 MB
    float* k1   = (float*)alloc((size_t)BSZ * C * 5 * 4);
    float* k2   = (float*)alloc((size_t)BSZ * C * 5 * 4);
    float* kn1  = (float*)alloc((size_t)BSZ * C * 5 * 4);
    float* kn2  = (float*)alloc((size_t)BSZ * C * 5 * 4);
    float* a1   = (float*)alloc((size_t)BSZ * C * 5 * 4);
    float* a2   = (float*)alloc((size_t)BSZ * C * 5 * 4);
    float* S1   = (float*)alloc((size_t)BSZ * C * 5 * 4);
    float* S2   = (float*)alloc((size_t)BSZ * C * 5 * 4);
    float* simA = (float*)alloc((size_t)BSZ * BSZ * 4);
    float* simB = (float*)alloc((size_t)BSZ * BSZ * 4);
    float* simT = (float*)alloc((size_t)BSZ * BSZ * 4);
    float* partials = (float*)alloc(64 * 256 * 2 * 4);
    float* scale = (float*)alloc(64 * 4);
    float* shift = (float*)alloc(64 * 4);
    float* losses = (float*)alloc(4 * 4);

    auto run_stage = [&](const float* xin, const float* wgt, const float* bias,
                         const float* g, const float* be,
                         int Cin, int Cout, int W, int K, int pad, int nchunk,
                         float* outp, bool pool) {
        dim3 gs(Cout, nchunk);
        conv_stats_kernel<<<gs, NTHR, 0, stream>>>(xin, wgt, bias, partials, Cin, W, K, pad, nchunk);
        stats_finalize_kernel<<<1, 64, 0, stream>>>(partials, nchunk, 1.f / ((float)BSZ * W),
                                                    g, be, scale, shift, Cout);
        if (pool) {
            long long total = (long long)BSZ * Cout * (W / 4);
            conv_bn_pool_kernel<<<ceil_divll(total, NTHR), NTHR, 0, stream>>>(
                xin, wgt, bias, scale, shift, outp, Cin, W, K, pad, Cout);
        } else {
            long long total = (long long)BSZ * Cout * W;
            conv_bn_relu_kernel<<<ceil_divll(total, NTHR), NTHR, 0, stream>>>(
                xin, wgt, bias, scale, shift, outp, Cin, W, K, pad, Cout);
        }
    };

    auto run_pass = [&](const float* x, float* hfin, float* kout) {
        run_stage(x,    w1, b1, g1, be1,  1, 16, 8192, 17, 8, 128, act0, true);  // ->(256,16,2048)
        run_stage(act0, w2, b2, g2, be2, 16, 32, 2048, 17, 8,  64, act1, true);  // ->(256,32,512)
        run_stage(act1, w3, b3, g3, be3, 32, 64,  512, 17, 8,  32, hfin, true);  // ->(256,64,128)
        run_stage(hfin, tw1, tb1, tg1, tbe1, 64, 64, 128, 5, 2, 16, act0, false);// ->(256,64,128)
        run_stage(act0, tw2, tb2, tg2, tbe2, 64, 64, 128, 3, 1, 16, act1, false);// ->(256,64,128)
        long long pt = (long long)BSZ * C * 5;
        adapool_kernel<<<ceil_divll(pt, NTHR), NTHR, 0, stream>>>(act1, kout, C, 128, 5);
    };

    run_pass(x1, h1f, k1);
    run_pass(x2, h2f, k2);

    const int nrows = BSZ * C;  // 16384
    knorm_kernel<<<ceil_divll(nrows, NTHR), NTHR, 0, stream>>>(k1, kn1, nrows);
    knorm_kernel<<<ceil_divll(nrows, NTHR), NTHR, 0, stream>>>(k2, kn2, nrows);
    srow_kernel<<<ceil_divll(nrows, NTHR), NTHR, 0, stream>>>(h1f, S1, nrows, 128);
    srow_kernel<<<ceil_divll(nrows, NTHR), NTHR, 0, stream>>>(h2f, S2, nrows, 128);
    flatnorm_kernel<<<1, NTHR, 0, stream>>>(k1, a1, BSZ, C * 5);
    flatnorm_kernel<<<1, NTHR, 0, stream>>>(k2, a2, BSZ, C * 5);

    dim3 sg(1, BSZ);
    simdot_kernel<<<sg, NTHR, 0, stream>>>(kn1, S2, simA, BSZ, C * 5, 1.f / 128.f);
    simdot_kernel<<<sg, NTHR, 0, stream>>>(kn2, S1, simB, BSZ, C * 5, 1.f / 128.f);
    simdot_kernel<<<sg, NTHR, 0, stream>>>(a1, a2, simT, BSZ, C * 5, 1.f);

    infonce_kernel<<<1, NTHR, 0, stream>>>(simA, BSZ, 10.f, losses + 0);
    infonce_kernel<<<1, NTHR, 0, stream>>>(simB, BSZ, 10.f, losses + 1);
    infonce_kernel<<<1, NTHR, 0, stream>>>(simT, BSZ, 10.f, losses + 2);
    final_kernel<<<1, 1, 0, stream>>>(losses, out);
}

// Round 2
// 2500.983 us; speedup vs baseline: 10.8023x; 10.8023x over previous
//
#include <hip/hip_runtime.h>
#include <math.h>

// ---------------------------------------------------------------------------
// TCCL model forward. Round 1: tiled LDS conv kernel, fully unrolled inner
// loops (zero-padding materialized in LDS), weight broadcast from LDS.
// Per stage: pass A = conv + per-channel block stats (no store);
//            finalize -> scale/shift;
//            pass B = recompute conv, BN+ReLU(+maxpool4), store.
// ---------------------------------------------------------------------------

#define BSZ 256
#define NTHR 256

static inline int ceil_divll(long long a, int b) { return (int)((a + b - 1) / b); }

// MODE: 0 = stats only, 1 = apply BN+ReLU+maxpool4, 2 = apply BN+ReLU
template<int CIN, int COUT, int K, int PAD, int TILE, int R, int CICHUNK, int MODE>
__global__ __launch_bounds__(COUT*(TILE/R))
void conv_fast(const float* __restrict__ x, const float* __restrict__ wgt,
               const float* __restrict__ bias, const float* __restrict__ scale,
               const float* __restrict__ shift, float* __restrict__ out,
               float* __restrict__ partials, int W)
{
    constexpr int G  = TILE / R;
    constexpr int NT = COUT * G;
    constexpr int XW = TILE + K - 1;
    __shared__ float xs[CICHUNK][XW];
    __shared__ float wsm[COUT][CICHUNK][K];

    const int tid  = threadIdx.x;
    const int co   = tid / G;
    const int g    = tid % G;
    const int ntile = W / TILE;
    const int b    = blockIdx.x / ntile;
    const int tile = blockIdx.x % ntile;
    const int w0   = tile * TILE;

    float acc[R];
#pragma unroll
    for (int r = 0; r < R; ++r) acc[r] = 0.f;

    for (int cib = 0; cib < CIN; cib += CICHUNK) {
        if (cib) __syncthreads();
        // stage weight chunk: COUT x CICHUNK x K
        for (int i = tid; i < COUT * CICHUNK * K; i += NT) {
            const int lco = i / (CICHUNK * K);
            const int rem = i % (CICHUNK * K);
            const int lci = rem / K;
            const int lt  = rem % K;
            wsm[lco][lci][lt] = wgt[((long long)lco * CIN + (cib + lci)) * K + lt];
        }
        // stage x tile with zero padding
        for (int i = tid; i < CICHUNK * XW; i += NT) {
            const int lci = i / XW;
            const int j   = i % XW;
            const int xw  = w0 - PAD + j;
            float v = 0.f;
            if (xw >= 0 && xw < W)
                v = x[((long long)b * CIN + (cib + lci)) * W + xw];
            xs[lci][j] = v;
        }
        __syncthreads();
#pragma unroll
        for (int ci = 0; ci < CICHUNK; ++ci) {
            float xr[R + K - 1];
#pragma unroll
            for (int j = 0; j < R + K - 1; ++j) xr[j] = xs[ci][g * R + j];
#pragma unroll
            for (int t = 0; t < K; ++t) {
                const float wv = wsm[co][ci][t];
#pragma unroll
                for (int r = 0; r < R; ++r) acc[r] = fmaf(xr[r + t], wv, acc[r]);
            }
        }
    }

    const float bi = bias[co];
    if (MODE == 0) {
        float s = 0.f, ss = 0.f;
#pragma unroll
        for (int r = 0; r < R; ++r) { const float y = acc[r] + bi; s += y; ss += y * y; }
        __shared__ float red[NT][2];
        red[tid][0] = s; red[tid][1] = ss;
        __syncthreads();
        if (tid < COUT) {
            float a = 0.f, bb = 0.f;
            for (int e = 0; e < G; ++e) { a += red[tid * G + e][0]; bb += red[tid * G + e][1]; }
            partials[((long long)blockIdx.x * COUT + tid) * 2 + 0] = a;
            partials[((long long)blockIdx.x * COUT + tid) * 2 + 1] = bb;
        }
    } else if (MODE == 1) {
        const float sc = scale[co], sh = shift[co];
        float* o = out + ((long long)b * COUT + co) * (W >> 2) + ((w0 + g * R) >> 2);
#pragma unroll
        for (int p = 0; p < R / 4; ++p) {
            float mx = 0.f;  // ReLU folded into max
#pragma unroll
            for (int q = 0; q < 4; ++q) mx = fmaxf(mx, sc * (acc[p * 4 + q] + bi) + sh);
            o[p] = mx;
        }
    } else {
        const float sc = scale[co], sh = shift[co];
        float* o = out + ((long long)b * COUT + co) * W + w0 + g * R;
#pragma unroll
        for (int r = 0; r < R; ++r) o[r] = fmaxf(sc * (acc[r] + bi) + sh, 0.f);
    }
}

// per-channel finalize: sum partials over blocks -> scale/shift. grid=COUT.
template<int COUT>
__global__ void finalize_kernel(const float* __restrict__ partials, int nblk, float invN,
                                const float* __restrict__ g, const float* __restrict__ be,
                                float* __restrict__ scale, float* __restrict__ shift)
{
    const int co = blockIdx.x;
    float s = 0.f, ss = 0.f;
    for (int i = threadIdx.x; i < nblk; i += NTHR) {
        s  += partials[((long long)i * COUT + co) * 2 + 0];
        ss += partials[((long long)i * COUT + co) * 2 + 1];
    }
    __shared__ float red[NTHR][2];
    red[threadIdx.x][0] = s; red[threadIdx.x][1] = ss;
    __syncthreads();
    for (int off = NTHR / 2; off > 0; off >>= 1) {
        if ((int)threadIdx.x < off) {
            red[threadIdx.x][0] += red[threadIdx.x + off][0];
            red[threadIdx.x][1] += red[threadIdx.x + off][1];
        }
        __syncthreads();
    }
    if (threadIdx.x == 0) {
        const float m = red[0][0] * invN;
        const float v = red[0][1] * invN - m * m;
        const float inv = rsqrtf(v + 1e-5f);
        const float sc = g[co] * inv;
        scale[co] = sc;
        shift[co] = be[co] - sc * m;
    }
}

// adaptive avg pool to K5 bins. in: (B,C,W) out: (B,C,K5)
__global__ void adapool_kernel(const float* __restrict__ in, float* __restrict__ out,
                               int C, int W, int K5)
{
    const long long total = (long long)BSZ * C * K5;
    for (long long i = (long long)blockIdx.x * NTHR + threadIdx.x; i < total;
         i += (long long)gridDim.x * NTHR) {
        const int kk = (int)(i % K5);
        const long long r = i / K5;
        const int c = (int)(r % C);
        const int b = (int)(r / C);
        const int s = (kk * W) / K5;
        const int e = ((kk + 1) * W + K5 - 1) / K5;
        const float* p = in + ((long long)b * C + c) * W;
        float acc = 0.f;
        for (int w = s; w < e; ++w) acc += p[w];
        out[i] = acc / (float)(e - s);
    }
}

// center + l2-normalize each (b,c) row of 5.
__global__ void knorm_kernel(const float* __restrict__ k, float* __restrict__ kn, int nrows)
{
    int i = blockIdx.x * NTHR + threadIdx.x;
    if (i >= nrows) return;
    const float* p = k + (long long)i * 5;
    float m = 0.f;
    for (int t = 0; t < 5; ++t) m += p[t];
    m *= 0.2f;
    float v[5]; float n2 = 0.f;
    for (int t = 0; t < 5; ++t) { v[t] = p[t] - m; n2 += v[t] * v[t]; }
    float n = fmaxf(sqrtf(n2), 1e-12f);
    for (int t = 0; t < 5; ++t) kn[(long long)i * 5 + t] = v[t] / n;
}

// center+normalize each (b,c) row of h (W=128), emit the 5 window sums.
// With sum(hn)==0: S = {-(h[W-2]+h[W-1]), -h[W-1], 0, -h[0], -(h[0]+h[1])}
__global__ void srow_kernel(const float* __restrict__ h, float* __restrict__ S, int nrows, int W)
{
    int i = blockIdx.x * NTHR + threadIdx.x;
    if (i >= nrows) return;
    const float* p = h + (long long)i * W;
    float m = 0.f;
    for (int w = 0; w < W; ++w) m += p[w];
    m /= (float)W;
    float n2 = 0.f;
    for (int w = 0; w < W; ++w) { float d = p[w] - m; n2 += d * d; }
    float n = fmaxf(sqrtf(n2), 1e-12f);
    float h0 = (p[0] - m) / n, h1 = (p[1] - m) / n;
    float hN1 = (p[W - 1] - m) / n, hN2 = (p[W - 2] - m) / n;
    float* o = S + (long long)i * 5;
    o[0] = -(hN2 + hN1);
    o[1] = -hN1;
    o[2] = 0.f;
    o[3] = -h0;
    o[4] = -(h0 + h1);
}

// l2-normalize flattened rows of length D.
__global__ void flatnorm_kernel(const float* __restrict__ k, float* __restrict__ out, int nrows, int D)
{
    int i = blockIdx.x * NTHR + threadIdx.x;
    if (i >= nrows) return;
    const float* p = k + (long long)i * D;
    float n2 = 0.f;
    for (int d = 0; d < D; ++d) n2 += p[d] * p[d];
    float n = fmaxf(sqrtf(n2), 1e-12f);
    float* o = out + (long long)i * D;
    for (int d = 0; d < D; ++d) o[d] = p[d] / n;
}

// out[i][j] = coef * dot(A[i], B[j]) over D.  grid=(1, n)
__global__ void simdot_kernel(const float* __restrict__ A, const float* __restrict__ Bm,
                              float* __restrict__ out, int n, int D, float coef)
{
    int j = blockIdx.x * NTHR + threadIdx.x;
    int i = blockIdx.y;
    if (j >= n) return;
    const float* a = A + (long long)i * D;
    const float* b = Bm + (long long)j * D;
    float acc = 0.f;
    for (int d = 0; d < D; ++d) acc += a[d] * b[d];
    out[(long long)i * n + j] = acc * coef;
}

// -mean_i log_softmax(sim*invT)[i,i].
__global__ void infonce_kernel(const float* __restrict__ sim, int n, float invT,
                               float* __restrict__ loss)
{
    int i = threadIdx.x;
    float lp = 0.f;
    if (i < n) {
        const float* row = sim + (long long)i * n;
        float mx = -INFINITY;
        for (int j = 0; j < n; ++j) mx = fmaxf(mx, row[j] * invT);
        float se = 0.f;
        for (int j = 0; j < n; ++j) se += expf(row[j] * invT - mx);
        float lse = mx + logf(se);
        lp = row[i] * invT - lse;
    }
    __shared__ float red[NTHR];
    red[threadIdx.x] = (i < n) ? lp : 0.f;
    __syncthreads();
    for (int off = NTHR / 2; off > 0; off >>= 1) {
        if ((int)threadIdx.x < off) red[threadIdx.x] += red[threadIdx.x + off];
        __syncthreads();
    }
    if (threadIdx.x == 0) *loss = -red[0] / (float)n;
}

__global__ void final_kernel(const float* __restrict__ l, float* __restrict__ out)
{
    out[0] = 0.5f * (l[0] + l[1]) + 0.5f * l[2];
}

// ---------------------------------------------------------------------------

extern "C" void kernel_launch(void* const* d_in, const int* in_sizes, int n_in,
                              void* d_out, int out_size, void* d_ws, size_t ws_size,
                              hipStream_t stream)
{
    const float* x1  = (const float*)d_in[0];
    const float* x2  = (const float*)d_in[1];
    const float* w1  = (const float*)d_in[2];
    const float* b1  = (const float*)d_in[3];
    const float* g1  = (const float*)d_in[4];
    const float* be1 = (const float*)d_in[5];
    const float* w2  = (const float*)d_in[6];
    const float* b2  = (const float*)d_in[7];
    const float* g2  = (const float*)d_in[8];
    const float* be2 = (const float*)d_in[9];
    const float* w3  = (const float*)d_in[10];
    const float* b3  = (const float*)d_in[11];
    const float* g3  = (const float*)d_in[12];
    const float* be3 = (const float*)d_in[13];
    const float* tw1 = (const float*)d_in[14];
    const float* tb1 = (const float*)d_in[15];
    const float* tg1 = (const float*)d_in[16];
    const float* tbe1= (const float*)d_in[17];
    const float* tw2 = (const float*)d_in[18];
    const float* tb2 = (const float*)d_in[19];
    const float* tg2 = (const float*)d_in[20];
    const float* tbe2= (const float*)d_in[21];
    float* out = (float*)d_out;

    char* ws = (char*)d_ws;
    size_t off = 0;
    auto alloc = [&](size_t bytes) -> void* {
        off = (off + 255) & ~(size_t)255;
        void* p = ws + off;
        off += bytes;
        return p;
    };
    const int C = 64;
    float* h1f  = (float*)alloc((size_t)BSZ * C * 128 * 4);
    float* h2f  = (float*)alloc((size_t)BSZ * C * 128 * 4);
    float* act0 = (float*)alloc((size_t)BSZ * 16 * 2048 * 4);
    float* act1 = (float*)alloc((size_t)BSZ * 32 * 512 * 4);
    float* k1   = (float*)alloc((size_t)BSZ * C * 5 * 4);
    float* k2   = (float*)alloc((size_t)BSZ * C * 5 * 4);
    float* kn1  = (float*)alloc((size_t)BSZ * C * 5 * 4);
    float* kn2  = (float*)alloc((size_t)BSZ * C * 5 * 4);
    float* a1   = (float*)alloc((size_t)BSZ * C * 5 * 4);
    float* a2   = (float*)alloc((size_t)BSZ * C * 5 * 4);
    float* S1   = (float*)alloc((size_t)BSZ * C * 5 * 4);
    float* S2   = (float*)alloc((size_t)BSZ * C * 5 * 4);
    float* simA = (float*)alloc((size_t)BSZ * BSZ * 4);
    float* simB = (float*)alloc((size_t)BSZ * BSZ * 4);
    float* simT = (float*)alloc((size_t)BSZ * BSZ * 4);
    float* partials = (float*)alloc((size_t)8192 * 64 * 2 * 4);  // 4 MB
    float* scale = (float*)alloc(64 * 4);
    float* shift = (float*)alloc(64 * 4);
    float* losses = (float*)alloc(4 * 4);

    // stage launcher: STATS pass -> finalize -> APPLY pass
    // stage 1: CIN=1, COUT=16, K=17, TILE=256, R=16, CICHUNK=1
    auto stage1 = [&](const float* xin, float* outp) {
        const int W = 8192, nblk = BSZ * (W / 256);
        conv_fast<1,16,17,8,256,16,1,0><<<nblk, 256, 0, stream>>>(xin, w1, b1, nullptr, nullptr, nullptr, partials, W);
        finalize_kernel<16><<<16, NTHR, 0, stream>>>(partials, nblk, 1.f/((float)BSZ*W), g1, be1, scale, shift);
        conv_fast<1,16,17,8,256,16,1,1><<<nblk, 256, 0, stream>>>(xin, w1, b1, scale, shift, outp, nullptr, W);
    };
    // stage 2: CIN=16, COUT=32, K=17, TILE=64, R=8, CICHUNK=16
    auto stage2 = [&](const float* xin, float* outp) {
        const int W = 2048, nblk = BSZ * (W / 64);
        conv_fast<16,32,17,8,64,8,16,0><<<nblk, 256, 0, stream>>>(xin, w2, b2, nullptr, nullptr, nullptr, partials, W);
        finalize_kernel<32><<<32, NTHR, 0, stream>>>(partials, nblk, 1.f/((float)BSZ*W), g2, be2, scale, shift);
        conv_fast<16,32,17,8,64,8,16,1><<<nblk, 256, 0, stream>>>(xin, w2, b2, scale, shift, outp, nullptr, W);
    };
    // stage 3: CIN=32, COUT=64, K=17, TILE=32, R=8, CICHUNK=8
    auto stage3 = [&](const float* xin, float* outp) {
        const int W = 512, nblk = BSZ * (W / 32);
        conv_fast<32,64,17,8,32,8,8,0><<<nblk, 256, 0, stream>>>(xin, w3, b3, nullptr, nullptr, nullptr, partials, W);
        finalize_kernel<64><<<64, NTHR, 0, stream>>>(partials, nblk, 1.f/((float)BSZ*W), g3, be3, scale, shift);
        conv_fast<32,64,17,8,32,8,8,1><<<nblk, 256, 0, stream>>>(xin, w3, b3, scale, shift, outp, nullptr, W);
    };
    // template 1: CIN=64, COUT=64, K=5, TILE=32, R=8, CICHUNK=16, no pool
    auto tstage1 = [&](const float* xin, float* outp) {
        const int W = 128, nblk = BSZ * (W / 32);
        conv_fast<64,64,5,2,32,8,16,0><<<nblk, 256, 0, stream>>>(xin, tw1, tb1, nullptr, nullptr, nullptr, partials, W);
        finalize_kernel<64><<<64, NTHR, 0, stream>>>(partials, nblk, 1.f/((float)BSZ*W), tg1, tbe1, scale, shift);
        conv_fast<64,64,5,2,32,8,16,2><<<nblk, 256, 0, stream>>>(xin, tw1, tb1, scale, shift, outp, nullptr, W);
    };
    // template 2: CIN=64, COUT=64, K=3, TILE=32, R=8, CICHUNK=16, no pool
    auto tstage2 = [&](const float* xin, float* outp) {
        const int W = 128, nblk = BSZ * (W / 32);
        conv_fast<64,64,3,1,32,8,16,0><<<nblk, 256, 0, stream>>>(xin, tw2, tb2, nullptr, nullptr, nullptr, partials, W);
        finalize_kernel<64><<<64, NTHR, 0, stream>>>(partials, nblk, 1.f/((float)BSZ*W), tg2, tbe2, scale, shift);
        conv_fast<64,64,3,1,32,8,16,2><<<nblk, 256, 0, stream>>>(xin, tw2, tb2, scale, shift, outp, nullptr, W);
    };

    auto run_pass = [&](const float* x, float* hfin, float* kout) {
        stage1(x, act0);        // -> (256,16,2048)
        stage2(act0, act1);     // -> (256,32,512)
        stage3(act1, hfin);     // -> (256,64,128)
        tstage1(hfin, act0);    // -> (256,64,128)  (reuse act0)
        tstage2(act0, act1);    // -> (256,64,128)  (reuse act1)
        long long pt = (long long)BSZ * C * 5;
        adapool_kernel<<<ceil_divll(pt, NTHR), NTHR, 0, stream>>>(act1, kout, C, 128, 5);
    };

    run_pass(x1, h1f, k1);
    run_pass(x2, h2f, k2);

    const int nrows = BSZ * C;
    knorm_kernel<<<ceil_divll(nrows, NTHR), NTHR, 0, stream>>>(k1, kn1, nrows);
    knorm_kernel<<<ceil_divll(nrows, NTHR), NTHR, 0, stream>>>(k2, kn2, nrows);
    srow_kernel<<<ceil_divll(nrows, NTHR), NTHR, 0, stream>>>(h1f, S1, nrows, 128);
    srow_kernel<<<ceil_divll(nrows, NTHR), NTHR, 0, stream>>>(h2f, S2, nrows, 128);
    flatnorm_kernel<<<1, NTHR, 0, stream>>>(k1, a1, BSZ, C * 5);
    flatnorm_kernel<<<1, NTHR, 0, stream>>>(k2, a2, BSZ, C * 5);

    dim3 sg(1, BSZ);
    simdot_kernel<<<sg, NTHR, 0, stream>>>(kn1, S2, simA, BSZ, C * 5, 1.f / 128.f);
    simdot_kernel<<<sg, NTHR, 0, stream>>>(kn2, S1, simB, BSZ, C * 5, 1.f / 128.f);
    simdot_kernel<<<sg, NTHR, 0, stream>>>(a1, a2, simT, BSZ, C * 5, 1.f);

    infonce_kernel<<<1, NTHR, 0, stream>>>(simA, BSZ, 10.f, losses + 0);
    infonce_kernel<<<1, NTHR, 0, stream>>>(simB, BSZ, 10.f, losses + 1);
    infonce_kernel<<<1, NTHR, 0, stream>>>(simT, BSZ, 10.f, losses + 2);
    final_kernel<<<1, 1, 0, stream>>>(losses, out);
}

// Round 3
// 1500.766 us; speedup vs baseline: 18.0017x; 1.6665x over previous
//
#include <hip/hip_runtime.h>
#include <math.h>

// ---------------------------------------------------------------------------
// TCCL model forward. Round 2:
//  - conv staging loops restructured to pow2-only index math (R1 post-mortem:
//    ~3:1 non-FMA:FMA VALU ratio traced to div/mod-by-17/48/80 in staging)
//  - smaller CICHUNK -> ~20 KB LDS -> 7 blocks/CU (occupancy 31% -> ~85%)
//  - stats pass materializes pre-BN conv output y (MODE 3); cheap vectorized
//    bn_apply/bn_pool_apply replaces the recompute conv pass for stages
//    2,3,t1,t2. Stage 1 (Cin=1, cheap) keeps recompute.
// ---------------------------------------------------------------------------

#define BSZ 256
#define NTHR 256

static inline int ceil_divll(long long a, int b) { return (int)((a + b - 1) / b); }

// MODE: 0 = stats only, 1 = apply BN+ReLU+maxpool4 (recompute path),
//       2 = apply BN+ReLU (recompute path), 3 = stats + store y
template<int CIN, int COUT, int K, int PAD, int TILE, int R, int CICHUNK, int MODE>
__global__ __launch_bounds__(COUT*(TILE/R))
void conv_fast(const float* __restrict__ x, const float* __restrict__ wgt,
               const float* __restrict__ bias, const float* __restrict__ scale,
               const float* __restrict__ shift, float* __restrict__ out,
               float* __restrict__ partials, int W, float* __restrict__ yout)
{
    constexpr int G  = TILE / R;
    constexpr int NT = COUT * G;
    constexpr int XW = TILE + K - 1;
    constexpr int PAIRS = COUT * CICHUNK;   // pow2
    constexpr int LPC = NT / CICHUNK;       // pow2, threads per ci row
    __shared__ float xs[CICHUNK][XW];
    __shared__ float wsm[COUT][CICHUNK][K];

    const int tid  = threadIdx.x;
    const int co   = tid / G;               // pow2
    const int g    = tid % G;               // pow2
    const int ntile = W / TILE;
    const int b    = blockIdx.x / ntile;
    const int tile = blockIdx.x % ntile;
    const int w0   = tile * TILE;

    float acc[R];
#pragma unroll
    for (int r = 0; r < R; ++r) acc[r] = 0.f;

    const int lci_x = tid / LPC;            // pow2 shift
    const int j0_x  = tid % LPC;            // pow2 mask

    for (int cib = 0; cib < CIN; cib += CICHUNK) {
        if (cib) __syncthreads();
        // ---- stage weights: pow2 pair mapping, K consecutive floats/thread
        if (PAIRS >= NT) {
#pragma unroll
            for (int p = 0; p < PAIRS / NT; ++p) {
                const int pair = p * NT + tid;
                const int lco = pair / CICHUNK;     // pow2
                const int lci = pair % CICHUNK;     // pow2
                const float* src = wgt + ((long long)lco * CIN + (cib + lci)) * K;
#pragma unroll
                for (int t = 0; t < K; ++t) wsm[lco][lci][t] = src[t];
            }
        } else {
            if (tid < PAIRS) {
                const int lco = tid / CICHUNK;
                const int lci = tid % CICHUNK;
                const float* src = wgt + ((long long)lco * CIN + (cib + lci)) * K;
#pragma unroll
                for (int t = 0; t < K; ++t) wsm[lco][lci][t] = src[t];
            }
        }
        // ---- stage x tile (zero-padded), pow2 row mapping, coalesced
        {
            const float* xrow = x + ((long long)b * CIN + (cib + lci_x)) * W;
#pragma unroll
            for (int it = 0; it * LPC < XW; ++it) {
                const int j = j0_x + it * LPC;
                if (j < XW) {
                    const int xw = w0 - PAD + j;
                    float v = 0.f;
                    if (xw >= 0 && xw < W) v = xrow[xw];
                    xs[lci_x][j] = v;
                }
            }
        }
        __syncthreads();
#pragma unroll
        for (int ci = 0; ci < CICHUNK; ++ci) {
            float xr[R + K - 1];
#pragma unroll
            for (int j = 0; j < R + K - 1; ++j) xr[j] = xs[ci][g * R + j];
#pragma unroll
            for (int t = 0; t < K; ++t) {
                const float wv = wsm[co][ci][t];
#pragma unroll
                for (int r = 0; r < R; ++r) acc[r] = fmaf(xr[r + t], wv, acc[r]);
            }
        }
    }

    const float bi = bias[co];
    if (MODE == 0 || MODE == 3) {
        if (MODE == 3) {
            float* o = yout + ((long long)b * COUT + co) * W + w0 + g * R;
#pragma unroll
            for (int r = 0; r < R; ++r) o[r] = acc[r] + bi;
        }
        float s = 0.f, ss = 0.f;
#pragma unroll
        for (int r = 0; r < R; ++r) { const float y = acc[r] + bi; s += y; ss += y * y; }
        __shared__ float red[NT][2];
        red[tid][0] = s; red[tid][1] = ss;
        __syncthreads();
        if (tid < COUT) {
            float a = 0.f, bb = 0.f;
            for (int e = 0; e < G; ++e) { a += red[tid * G + e][0]; bb += red[tid * G + e][1]; }
            partials[((long long)blockIdx.x * COUT + tid) * 2 + 0] = a;
            partials[((long long)blockIdx.x * COUT + tid) * 2 + 1] = bb;
        }
    } else if (MODE == 1) {
        const float sc = scale[co], sh = shift[co];
        float* o = out + ((long long)b * COUT + co) * (W >> 2) + ((w0 + g * R) >> 2);
#pragma unroll
        for (int p = 0; p < R / 4; ++p) {
            float mx = 0.f;  // ReLU folded into max
#pragma unroll
            for (int q = 0; q < 4; ++q) mx = fmaxf(mx, sc * (acc[p * 4 + q] + bi) + sh);
            o[p] = mx;
        }
    } else {
        const float sc = scale[co], sh = shift[co];
        float* o = out + ((long long)b * COUT + co) * W + w0 + g * R;
#pragma unroll
        for (int r = 0; r < R; ++r) o[r] = fmaxf(sc * (acc[r] + bi) + sh, 0.f);
    }
}

// per-channel finalize: sum partials over blocks -> scale/shift. grid=COUT.
template<int COUT>
__global__ void finalize_kernel(const float* __restrict__ partials, int nblk, float invN,
                                const float* __restrict__ g, const float* __restrict__ be,
                                float* __restrict__ scale, float* __restrict__ shift)
{
    const int co = blockIdx.x;
    float s = 0.f, ss = 0.f;
    for (int i = threadIdx.x; i < nblk; i += NTHR) {
        s  += partials[((long long)i * COUT + co) * 2 + 0];
        ss += partials[((long long)i * COUT + co) * 2 + 1];
    }
    __shared__ float red[NTHR][2];
    red[threadIdx.x][0] = s; red[threadIdx.x][1] = ss;
    __syncthreads();
    for (int off = NTHR / 2; off > 0; off >>= 1) {
        if ((int)threadIdx.x < off) {
            red[threadIdx.x][0] += red[threadIdx.x + off][0];
            red[threadIdx.x][1] += red[threadIdx.x + off][1];
        }
        __syncthreads();
    }
    if (threadIdx.x == 0) {
        const float m = red[0][0] * invN;
        const float v = red[0][1] * invN - m * m;
        const float inv = rsqrtf(v + 1e-5f);
        const float sc = g[co] * inv;
        scale[co] = sc;
        shift[co] = be[co] - sc * m;
    }
}

// BN+ReLU+maxpool4 from materialized y. WP = pooled width (pow2).
template<int C, int WP>
__global__ void bn_pool_apply(const float* __restrict__ y, const float* __restrict__ scale,
                              const float* __restrict__ shift, float* __restrict__ out)
{
    const int total = BSZ * C * WP;
    for (int i = blockIdx.x * NTHR + threadIdx.x; i < total; i += gridDim.x * NTHR) {
        const int c = (i / WP) % C;          // pow2
        const float sc = scale[c], sh = shift[c];
        const float4 v = ((const float4*)y)[i];
        float mx = 0.f;
        mx = fmaxf(mx, fmaf(sc, v.x, sh));
        mx = fmaxf(mx, fmaf(sc, v.y, sh));
        mx = fmaxf(mx, fmaf(sc, v.z, sh));
        mx = fmaxf(mx, fmaf(sc, v.w, sh));
        out[i] = mx;
    }
}

// BN+ReLU (no pool) from materialized y. W4 = W/4 (pow2).
template<int C, int W4>
__global__ void bn_apply(const float* __restrict__ y, const float* __restrict__ scale,
                         const float* __restrict__ shift, float* __restrict__ out)
{
    const int total = BSZ * C * W4;
    for (int i = blockIdx.x * NTHR + threadIdx.x; i < total; i += gridDim.x * NTHR) {
        const int c = (i / W4) % C;          // pow2
        const float sc = scale[c], sh = shift[c];
        const float4 v = ((const float4*)y)[i];
        float4 o;
        o.x = fmaxf(fmaf(sc, v.x, sh), 0.f);
        o.y = fmaxf(fmaf(sc, v.y, sh), 0.f);
        o.z = fmaxf(fmaf(sc, v.z, sh), 0.f);
        o.w = fmaxf(fmaf(sc, v.w, sh), 0.f);
        ((float4*)out)[i] = o;
    }
}

// adaptive avg pool to K5 bins. in: (B,C,W) out: (B,C,K5)
__global__ void adapool_kernel(const float* __restrict__ in, float* __restrict__ out,
                               int C, int W, int K5)
{
    const long long total = (long long)BSZ * C * K5;
    for (long long i = (long long)blockIdx.x * NTHR + threadIdx.x; i < total;
         i += (long long)gridDim.x * NTHR) {
        const int kk = (int)(i % K5);
        const long long r = i / K5;
        const int c = (int)(r % C);
        const int b = (int)(r / C);
        const int s = (kk * W) / K5;
        const int e = ((kk + 1) * W + K5 - 1) / K5;
        const float* p = in + ((long long)b * C + c) * W;
        float acc = 0.f;
        for (int w = s; w < e; ++w) acc += p[w];
        out[i] = acc / (float)(e - s);
    }
}

__global__ void knorm_kernel(const float* __restrict__ k, float* __restrict__ kn, int nrows)
{
    int i = blockIdx.x * NTHR + threadIdx.x;
    if (i >= nrows) return;
    const float* p = k + (long long)i * 5;
    float m = 0.f;
    for (int t = 0; t < 5; ++t) m += p[t];
    m *= 0.2f;
    float v[5]; float n2 = 0.f;
    for (int t = 0; t < 5; ++t) { v[t] = p[t] - m; n2 += v[t] * v[t]; }
    float n = fmaxf(sqrtf(n2), 1e-12f);
    for (int t = 0; t < 5; ++t) kn[(long long)i * 5 + t] = v[t] / n;
}

// center+normalize each (b,c) row of h (W=128), emit the 5 window sums.
// With sum(hn)==0: S = {-(h[W-2]+h[W-1]), -h[W-1], 0, -h[0], -(h[0]+h[1])}
__global__ void srow_kernel(const float* __restrict__ h, float* __restrict__ S, int nrows, int W)
{
    int i = blockIdx.x * NTHR + threadIdx.x;
    if (i >= nrows) return;
    const float* p = h + (long long)i * W;
    float m = 0.f;
    for (int w = 0; w < W; ++w) m += p[w];
    m /= (float)W;
    float n2 = 0.f;
    for (int w = 0; w < W; ++w) { float d = p[w] - m; n2 += d * d; }
    float n = fmaxf(sqrtf(n2), 1e-12f);
    float h0 = (p[0] - m) / n, h1 = (p[1] - m) / n;
    float hN1 = (p[W - 1] - m) / n, hN2 = (p[W - 2] - m) / n;
    float* o = S + (long long)i * 5;
    o[0] = -(hN2 + hN1);
    o[1] = -hN1;
    o[2] = 0.f;
    o[3] = -h0;
    o[4] = -(h0 + h1);
}

__global__ void flatnorm_kernel(const float* __restrict__ k, float* __restrict__ out, int nrows, int D)
{
    int i = blockIdx.x * NTHR + threadIdx.x;
    if (i >= nrows) return;
    const float* p = k + (long long)i * D;
    float n2 = 0.f;
    for (int d = 0; d < D; ++d) n2 += p[d] * p[d];
    float n = fmaxf(sqrtf(n2), 1e-12f);
    float* o = out + (long long)i * D;
    for (int d = 0; d < D; ++d) o[d] = p[d] / n;
}

__global__ void simdot_kernel(const float* __restrict__ A, const float* __restrict__ Bm,
                              float* __restrict__ out, int n, int D, float coef)
{
    int j = blockIdx.x * NTHR + threadIdx.x;
    int i = blockIdx.y;
    if (j >= n) return;
    const float* a = A + (long long)i * D;
    const float* b = Bm + (long long)j * D;
    float acc = 0.f;
    for (int d = 0; d < D; ++d) acc += a[d] * b[d];
    out[(long long)i * n + j] = acc * coef;
}

__global__ void infonce_kernel(const float* __restrict__ sim, int n, float invT,
                               float* __restrict__ loss)
{
    int i = threadIdx.x;
    float lp = 0.f;
    if (i < n) {
        const float* row = sim + (long long)i * n;
        float mx = -INFINITY;
        for (int j = 0; j < n; ++j) mx = fmaxf(mx, row[j] * invT);
        float se = 0.f;
        for (int j = 0; j < n; ++j) se += expf(row[j] * invT - mx);
        float lse = mx + logf(se);
        lp = row[i] * invT - lse;
    }
    __shared__ float red[NTHR];
    red[threadIdx.x] = (i < n) ? lp : 0.f;
    __syncthreads();
    for (int off = NTHR / 2; off > 0; off >>= 1) {
        if ((int)threadIdx.x < off) red[threadIdx.x] += red[threadIdx.x + off];
        __syncthreads();
    }
    if (threadIdx.x == 0) *loss = -red[0] / (float)n;
}

__global__ void final_kernel(const float* __restrict__ l, float* __restrict__ out)
{
    out[0] = 0.5f * (l[0] + l[1]) + 0.5f * l[2];
}

// ---------------------------------------------------------------------------

extern "C" void kernel_launch(void* const* d_in, const int* in_sizes, int n_in,
                              void* d_out, int out_size, void* d_ws, size_t ws_size,
                              hipStream_t stream)
{
    const float* x1  = (const float*)d_in[0];
    const float* x2  = (const float*)d_in[1];
    const float* w1  = (const float*)d_in[2];
    const float* b1  = (const float*)d_in[3];
    const float* g1  = (const float*)d_in[4];
    const float* be1 = (const float*)d_in[5];
    const float* w2  = (const float*)d_in[6];
    const float* b2  = (const float*)d_in[7];
    const float* g2  = (const float*)d_in[8];
    const float* be2 = (const float*)d_in[9];
    const float* w3  = (const float*)d_in[10];
    const float* b3  = (const float*)d_in[11];
    const float* g3  = (const float*)d_in[12];
    const float* be3 = (const float*)d_in[13];
    const float* tw1 = (const float*)d_in[14];
    const float* tb1 = (const float*)d_in[15];
    const float* tg1 = (const float*)d_in[16];
    const float* tbe1= (const float*)d_in[17];
    const float* tw2 = (const float*)d_in[18];
    const float* tb2 = (const float*)d_in[19];
    const float* tg2 = (const float*)d_in[20];
    const float* tbe2= (const float*)d_in[21];
    float* out = (float*)d_out;

    char* ws = (char*)d_ws;
    size_t off = 0;
    auto alloc = [&](size_t bytes) -> void* {
        off = (off + 255) & ~(size_t)255;
        void* p = ws + off;
        off += bytes;
        return p;
    };
    const int C = 64;
    float* h1f  = (float*)alloc((size_t)BSZ * C * 128 * 4);
    float* h2f  = (float*)alloc((size_t)BSZ * C * 128 * 4);
    float* act0 = (float*)alloc((size_t)BSZ * 16 * 2048 * 4);
    float* act1 = (float*)alloc((size_t)BSZ * 32 * 512 * 4);
    float* k1   = (float*)alloc((size_t)BSZ * C * 5 * 4);
    float* k2   = (float*)alloc((size_t)BSZ * C * 5 * 4);
    float* kn1  = (float*)alloc((size_t)BSZ * C * 5 * 4);
    float* kn2  = (float*)alloc((size_t)BSZ * C * 5 * 4);
    float* a1   = (float*)alloc((size_t)BSZ * C * 5 * 4);
    float* a2   = (float*)alloc((size_t)BSZ * C * 5 * 4);
    float* S1   = (float*)alloc((size_t)BSZ * C * 5 * 4);
    float* S2   = (float*)alloc((size_t)BSZ * C * 5 * 4);
    float* simA = (float*)alloc((size_t)BSZ * BSZ * 4);
    float* simB = (float*)alloc((size_t)BSZ * BSZ * 4);
    float* simT = (float*)alloc((size_t)BSZ * BSZ * 4);
    float* partials = (float*)alloc((size_t)8192 * 64 * 2 * 4);  // 4 MB
    float* scale = (float*)alloc(64 * 4);
    float* shift = (float*)alloc(64 * 4);
    float* losses = (float*)alloc(4 * 4);
    // big scratch for materialized conv outputs (stage2 is largest: 67 MB)
    float* ybuf = (float*)alloc((size_t)BSZ * 32 * 2048 * 4);
    const bool use_mat = (off <= ws_size);   // deterministic fallback

    // ---- stage 1 (recompute path; Cin=1 conv is cheap) ----
    auto stage1 = [&](const float* xin, float* outp) {
        const int W = 8192, nblk = BSZ * (W / 256);
        conv_fast<1,16,17,8,256,16,1,0><<<nblk, 256, 0, stream>>>(xin, w1, b1, nullptr, nullptr, nullptr, partials, W, nullptr);
        finalize_kernel<16><<<16, NTHR, 0, stream>>>(partials, nblk, 1.f/((float)BSZ*W), g1, be1, scale, shift);
        conv_fast<1,16,17,8,256,16,1,1><<<nblk, 256, 0, stream>>>(xin, w1, b1, scale, shift, outp, nullptr, W, nullptr);
    };
    // ---- stage 2: CICHUNK=8 (22 KB LDS) ----
    auto stage2 = [&](const float* xin, float* outp) {
        const int W = 2048, nblk = BSZ * (W / 64);
        if (use_mat) {
            conv_fast<16,32,17,8,64,8,8,3><<<nblk, 256, 0, stream>>>(xin, w2, b2, nullptr, nullptr, nullptr, partials, W, ybuf);
            finalize_kernel<32><<<32, NTHR, 0, stream>>>(partials, nblk, 1.f/((float)BSZ*W), g2, be2, scale, shift);
            bn_pool_apply<32,512><<<2048, NTHR, 0, stream>>>(ybuf, scale, shift, outp);
        } else {
            conv_fast<16,32,17,8,64,8,8,0><<<nblk, 256, 0, stream>>>(xin, w2, b2, nullptr, nullptr, nullptr, partials, W, nullptr);
            finalize_kernel<32><<<32, NTHR, 0, stream>>>(partials, nblk, 1.f/((float)BSZ*W), g2, be2, scale, shift);
            conv_fast<16,32,17,8,64,8,8,1><<<nblk, 256, 0, stream>>>(xin, w2, b2, scale, shift, outp, nullptr, W, nullptr);
        }
    };
    // ---- stage 3: CICHUNK=4 (20 KB LDS) ----
    auto stage3 = [&](const float* xin, float* outp) {
        const int W = 512, nblk = BSZ * (W / 32);
        if (use_mat) {
            conv_fast<32,64,17,8,32,8,4,3><<<nblk, 256, 0, stream>>>(xin, w3, b3, nullptr, nullptr, nullptr, partials, W, ybuf);
            finalize_kernel<64><<<64, NTHR, 0, stream>>>(partials, nblk, 1.f/((float)BSZ*W), g3, be3, scale, shift);
            bn_pool_apply<64,128><<<2048, NTHR, 0, stream>>>(ybuf, scale, shift, outp);
        } else {
            conv_fast<32,64,17,8,32,8,4,0><<<nblk, 256, 0, stream>>>(xin, w3, b3, nullptr, nullptr, nullptr, partials, W, nullptr);
            finalize_kernel<64><<<64, NTHR, 0, stream>>>(partials, nblk, 1.f/((float)BSZ*W), g3, be3, scale, shift);
            conv_fast<32,64,17,8,32,8,4,1><<<nblk, 256, 0, stream>>>(xin, w3, b3, scale, shift, outp, nullptr, W, nullptr);
        }
    };
    // ---- template stage 1: K=5, CICHUNK=8 ----
    auto tstage1 = [&](const float* xin, float* outp) {
        const int W = 128, nblk = BSZ * (W / 32);
        if (use_mat) {
            conv_fast<64,64,5,2,32,8,8,3><<<nblk, 256, 0, stream>>>(xin, tw1, tb1, nullptr, nullptr, nullptr, partials, W, ybuf);
            finalize_kernel<64><<<64, NTHR, 0, stream>>>(partials, nblk, 1.f/((float)BSZ*W), tg1, tbe1, scale, shift);
            bn_apply<64,32><<<2048, NTHR, 0, stream>>>(ybuf, scale, shift, outp);
        } else {
            conv_fast<64,64,5,2,32,8,8,0><<<nblk, 256, 0, stream>>>(xin, tw1, tb1, nullptr, nullptr, nullptr, partials, W, nullptr);
            finalize_kernel<64><<<64, NTHR, 0, stream>>>(partials, nblk, 1.f/((float)BSZ*W), tg1, tbe1, scale, shift);
            conv_fast<64,64,5,2,32,8,8,2><<<nblk, 256, 0, stream>>>(xin, tw1, tb1, scale, shift, outp, nullptr, W, nullptr);
        }
    };
    // ---- template stage 2: K=3, CICHUNK=8 ----
    auto tstage2 = [&](const float* xin, float* outp) {
        const int W = 128, nblk = BSZ * (W / 32);
        if (use_mat) {
            conv_fast<64,64,3,1,32,8,8,3><<<nblk, 256, 0, stream>>>(xin, tw2, tb2, nullptr, nullptr, nullptr, partials, W, ybuf);
            finalize_kernel<64><<<64, NTHR, 0, stream>>>(partials, nblk, 1.f/((float)BSZ*W), tg2, tbe2, scale, shift);
            bn_apply<64,32><<<2048, NTHR, 0, stream>>>(ybuf, scale, shift, outp);
        } else {
            conv_fast<64,64,3,1,32,8,8,0><<<nblk, 256, 0, stream>>>(xin, tw2, tb2, nullptr, nullptr, nullptr, partials, W, nullptr);
            finalize_kernel<64><<<64, NTHR, 0, stream>>>(partials, nblk, 1.f/((float)BSZ*W), tg2, tbe2, scale, shift);
            conv_fast<64,64,3,1,32,8,8,2><<<nblk, 256, 0, stream>>>(xin, tw2, tb2, scale, shift, outp, nullptr, W, nullptr);
        }
    };

    auto run_pass = [&](const float* x, float* hfin, float* kout) {
        stage1(x, act0);        // -> (256,16,2048)
        stage2(act0, act1);     // -> (256,32,512)
        stage3(act1, hfin);     // -> (256,64,128)
        tstage1(hfin, act0);    // -> (256,64,128)
        tstage2(act0, act1);    // -> (256,64,128)
        long long pt = (long long)BSZ * C * 5;
        adapool_kernel<<<ceil_divll(pt, NTHR), NTHR, 0, stream>>>(act1, kout, C, 128, 5);
    };

    run_pass(x1, h1f, k1);
    run_pass(x2, h2f, k2);

    const int nrows = BSZ * C;
    knorm_kernel<<<ceil_divll(nrows, NTHR), NTHR, 0, stream>>>(k1, kn1, nrows);
    knorm_kernel<<<ceil_divll(nrows, NTHR), NTHR, 0, stream>>>(k2, kn2, nrows);
    srow_kernel<<<ceil_divll(nrows, NTHR), NTHR, 0, stream>>>(h1f, S1, nrows, 128);
    srow_kernel<<<ceil_divll(nrows, NTHR), NTHR, 0, stream>>>(h2f, S2, nrows, 128);
    flatnorm_kernel<<<1, NTHR, 0, stream>>>(k1, a1, BSZ, C * 5);
    flatnorm_kernel<<<1, NTHR, 0, stream>>>(k2, a2, BSZ, C * 5);

    dim3 sg(1, BSZ);
    simdot_kernel<<<sg, NTHR, 0, stream>>>(kn1, S2, simA, BSZ, C * 5, 1.f / 128.f);
    simdot_kernel<<<sg, NTHR, 0, stream>>>(kn2, S1, simB, BSZ, C * 5, 1.f / 128.f);
    simdot_kernel<<<sg, NTHR, 0, stream>>>(a1, a2, simT, BSZ, C * 5, 1.f);

    infonce_kernel<<<1, NTHR, 0, stream>>>(simA, BSZ, 10.f, losses + 0);
    infonce_kernel<<<1, NTHR, 0, stream>>>(simB, BSZ, 10.f, losses + 1);
    infonce_kernel<<<1, NTHR, 0, stream>>>(simT, BSZ, 10.f, losses + 2);
    final_kernel<<<1, 1, 0, stream>>>(losses, out);
}

// Round 4
// 1027.251 us; speedup vs baseline: 26.2996x; 1.4610x over previous
//
#include <hip/hip_runtime.h>
#include <math.h>

// ---------------------------------------------------------------------------
// TCCL model forward. Round 3: bf16 MFMA conv for stages 2,3,t1,t2.
//  - conv as implicit GEMM: D[co][w] = sum_k A[co][k] B[k][w], K packed in
//    32-slices (stage2: t-pairs x 16ci; others: 32ci per t).
//  - activations stored bf16 TRANSPOSED [b][w][c]; LDS staging = linear copy;
//    B-fragment = one ds_read_b128 per lane (row stride CIN*2+16 -> 2-way ok)
//  - weights prepacked once per launch into MFMA A-frag layout (L2-resident)
//  - BN stats from materialized bf16 y; BN+ReLU(+pool) elementwise kernels
//  - stage1 (Cin=1) stays fp32 vector conv, writes bf16-transposed output
// ---------------------------------------------------------------------------

#define BSZ 256
#define NTHR 256

typedef __attribute__((ext_vector_type(8))) short bf16x8;
typedef __attribute__((ext_vector_type(4))) float f32x4;

static inline int ceil_divll(long long a, int b) { return (int)((a + b - 1) / b); }

__device__ __forceinline__ unsigned short f2bf(float f) {
    unsigned u = __float_as_uint(f);
    u = (u + 0x7FFFu + ((u >> 16) & 1u)) >> 16;
    return (unsigned short)u;
}
__device__ __forceinline__ float bf2f(unsigned short h) {
    return __uint_as_float(((unsigned)h) << 16);
}

// ---------------- stage 1: fp32 vector conv (Cin=1) -------------------------
// MODE 0 = stats only; MODE 4 = BN+ReLU+maxpool4, write bf16 transposed [b][wp][co]
template<int CIN, int COUT, int K, int PAD, int TILE, int R, int CICHUNK, int MODE>
__global__ __launch_bounds__(COUT*(TILE/R))
void conv_fast(const float* __restrict__ x, const float* __restrict__ wgt,
               const float* __restrict__ bias, const float* __restrict__ scale,
               const float* __restrict__ shift, void* __restrict__ out,
               float* __restrict__ partials, int W)
{
    constexpr int G  = TILE / R;
    constexpr int NT = COUT * G;
    constexpr int XW = TILE + K - 1;
    constexpr int LPC = NT / CICHUNK;
    __shared__ float xs[CICHUNK][XW];
    __shared__ float wsm[COUT][CICHUNK][K];

    const int tid  = threadIdx.x;
    const int co   = tid / G;
    const int g    = tid % G;
    const int ntile = W / TILE;
    const int b    = blockIdx.x / ntile;
    const int tile = blockIdx.x % ntile;
    const int w0   = tile * TILE;

    float acc[R];
#pragma unroll
    for (int r = 0; r < R; ++r) acc[r] = 0.f;

    const int lci_x = tid / LPC;
    const int j0_x  = tid % LPC;

    for (int cib = 0; cib < CIN; cib += CICHUNK) {
        if (cib) __syncthreads();
        if (tid < COUT * CICHUNK) {
            const int lco = tid / CICHUNK;
            const int lci = tid % CICHUNK;
            const float* src = wgt + ((long long)lco * CIN + (cib + lci)) * K;
#pragma unroll
            for (int t = 0; t < K; ++t) wsm[lco][lci][t] = src[t];
        }
        {
            const float* xrow = x + ((long long)b * CIN + (cib + lci_x)) * W;
#pragma unroll
            for (int it = 0; it * LPC < XW; ++it) {
                const int j = j0_x + it * LPC;
                if (j < XW) {
                    const int xw = w0 - PAD + j;
                    float v = 0.f;
                    if (xw >= 0 && xw < W) v = xrow[xw];
                    xs[lci_x][j] = v;
                }
            }
        }
        __syncthreads();
#pragma unroll
        for (int ci = 0; ci < CICHUNK; ++ci) {
            float xr[R + K - 1];
#pragma unroll
            for (int j = 0; j < R + K - 1; ++j) xr[j] = xs[ci][g * R + j];
#pragma unroll
            for (int t = 0; t < K; ++t) {
                const float wv = wsm[co][ci][t];
#pragma unroll
                for (int r = 0; r < R; ++r) acc[r] = fmaf(xr[r + t], wv, acc[r]);
            }
        }
    }

    const float bi = bias[co];
    if (MODE == 0) {
        float s = 0.f, ss = 0.f;
#pragma unroll
        for (int r = 0; r < R; ++r) { const float y = acc[r] + bi; s += y; ss += y * y; }
        __shared__ float red[NT][2];
        red[tid][0] = s; red[tid][1] = ss;
        __syncthreads();
        if (tid < COUT) {
            float a = 0.f, bb = 0.f;
            for (int e = 0; e < G; ++e) { a += red[tid * G + e][0]; bb += red[tid * G + e][1]; }
            partials[((long long)blockIdx.x * COUT + tid) * 2 + 0] = a;
            partials[((long long)blockIdx.x * COUT + tid) * 2 + 1] = bb;
        }
    } else {  // MODE 4
        const float sc = scale[co], sh = shift[co];
        unsigned short* o = (unsigned short*)out;
        const int wp0 = (w0 + g * R) >> 2;
#pragma unroll
        for (int p = 0; p < R / 4; ++p) {
            float mx = 0.f;
#pragma unroll
            for (int q = 0; q < 4; ++q) mx = fmaxf(mx, fmaf(sc, acc[p * 4 + q] + bi, sh));
            o[((long long)b * (W >> 2) + wp0 + p) * COUT + co] = f2bf(mx);
        }
    }
}

// per-channel finalize: sum partials over blocks -> scale/shift. grid=COUT.
template<int COUT>
__global__ void finalize_kernel(const float* __restrict__ partials, int nblk, float invN,
                                const float* __restrict__ g, const float* __restrict__ be,
                                float* __restrict__ scale, float* __restrict__ shift)
{
    const int co = blockIdx.x;
    float s = 0.f, ss = 0.f;
    for (int i = threadIdx.x; i < nblk; i += NTHR) {
        s  += partials[((long long)i * COUT + co) * 2 + 0];
        ss += partials[((long long)i * COUT + co) * 2 + 1];
    }
    __shared__ float red[NTHR][2];
    red[threadIdx.x][0] = s; red[threadIdx.x][1] = ss;
    __syncthreads();
    for (int off = NTHR / 2; off > 0; off >>= 1) {
        if ((int)threadIdx.x < off) {
            red[threadIdx.x][0] += red[threadIdx.x + off][0];
            red[threadIdx.x][1] += red[threadIdx.x + off][1];
        }
        __syncthreads();
    }
    if (threadIdx.x == 0) {
        const float m = red[0][0] * invN;
        const float v = red[0][1] * invN - m * m;
        const float inv = rsqrtf(v + 1e-5f);
        const float sc = g[co] * inv;
        scale[co] = sc;
        shift[co] = be[co] - sc * m;
    }
}

// ---------------- weight prepack into MFMA A-frag layout --------------------
// wp[((p*S+s)*CT+ct)*512 + lane*8 + j] = W[co][ci][t] as bf16
// co = ct*16+(lane&15); k = (lane>>4)*8+j;
// DT==2 (CIN=16): ci=k&15, t=p*2+(k>>4);  DT==1: ci=s*32+k, t=p.
template<int CIN, int KK, int DT, int NP, int S, int CT>
__global__ void build_wpack(const float* __restrict__ wgt, unsigned short* __restrict__ wp)
{
    const int idx = blockIdx.x * NTHR + threadIdx.x;
    constexpr int TOT = NP * S * CT * 512;
    if (idx >= TOT) return;
    const int j = idx & 7;
    const int l = (idx >> 3) & 63;
    int rest = idx >> 9;
    const int ct = rest % CT; rest /= CT;
    const int s = rest % S;
    const int p = rest / S;
    const int co = ct * 16 + (l & 15);
    const int k = (l >> 4) * 8 + j;
    int ci, t;
    if (DT == 2) { ci = k & (CIN - 1); t = p * 2 + (k >> 4); }
    else         { ci = s * 32 + k;    t = p; }
    float v = (t < KK) ? wgt[((long long)co * CIN + ci) * KK + t] : 0.f;
    wp[idx] = f2bf(v);
}

// ---------------- MFMA conv -------------------------------------------------
// xT: [b][W][CIN] bf16.  yT: [b][W][COUT] bf16 (= conv + bias, pre-BN).
template<int CIN, int COUT, int KK, int PAD, int DT, int NP, int S, int CT, int ST>
__global__ __launch_bounds__(256)
void conv_mfma(const unsigned short* __restrict__ xT, const unsigned short* __restrict__ wpack,
               const float* __restrict__ bias, unsigned short* __restrict__ yT, int W)
{
    constexpr int CHUNK = 4 * ST * 16;
    constexpr int ROWB = CIN * 2 + 16;
    constexpr int ROWS = CHUNK + KK + (DT - 1) + 1;
    constexpr int DPR = CIN / 2;      // dwords per source row
    __shared__ __align__(16) unsigned char lx[ROWS * ROWB];

    const int tid = threadIdx.x;
    const int ntile = W / CHUNK;
    const int b = blockIdx.x / ntile;
    const int tile = blockIdx.x % ntile;
    const int w0 = tile * CHUNK;

    // stage x window (zero-padded, transposed layout already) -> LDS
    for (int d = tid; d < ROWS * DPR; d += 256) {
        const int row = d / DPR;
        const int col = d % DPR;
        const int gw = w0 - PAD + row;
        unsigned v = 0;
        if (gw >= 0 && gw < W)
            v = *(const unsigned*)(xT + (((long long)b * W + gw) * CIN + col * 2));
        *(unsigned*)(lx + row * ROWB + col * 4) = v;
    }
    __syncthreads();

    const int lane = tid & 63, wave = tid >> 6;
    const int n = lane & 15, kq = lane >> 4;
    int rowbase, cbyte;
    if (DT == 2) { rowbase = wave * ST * 16 + n + (kq >> 1); cbyte = (kq & 1) * 16; }
    else         { rowbase = wave * ST * 16 + n;             cbyte = kq * 16; }

    f32x4 acc[ST][CT];
#pragma unroll
    for (int st = 0; st < ST; ++st)
#pragma unroll
        for (int ct = 0; ct < CT; ++ct) { acc[st][ct][0]=0.f; acc[st][ct][1]=0.f; acc[st][ct][2]=0.f; acc[st][ct][3]=0.f; }

#pragma unroll
    for (int p = 0; p < NP; ++p) {
#pragma unroll
        for (int s = 0; s < S; ++s) {
            bf16x8 a[CT];
#pragma unroll
            for (int ct = 0; ct < CT; ++ct)
                a[ct] = *(const bf16x8*)(wpack + (((long long)(p * S + s) * CT + ct) * 64 + lane) * 8);
#pragma unroll
            for (int st = 0; st < ST; ++st) {
                const int r = rowbase + st * 16 + p * DT;
                const bf16x8 bf = *(const bf16x8*)(lx + r * ROWB + cbyte + s * 64);
#pragma unroll
                for (int ct = 0; ct < CT; ++ct)
                    acc[st][ct] = __builtin_amdgcn_mfma_f32_16x16x32_bf16(a[ct], bf, acc[st][ct], 0, 0, 0);
            }
        }
    }

    // epilogue: add bias, cvt bf16, store transposed (4 consecutive co per lane)
#pragma unroll
    for (int st = 0; st < ST; ++st) {
        const int w = w0 + wave * ST * 16 + st * 16 + n;
        unsigned short* orow = yT + ((long long)b * W + w) * COUT;
#pragma unroll
        for (int ct = 0; ct < CT; ++ct) {
            const float* bp = bias + ct * 16 + kq * 4;
            const float v0 = acc[st][ct][0] + bp[0];
            const float v1 = acc[st][ct][1] + bp[1];
            const float v2 = acc[st][ct][2] + bp[2];
            const float v3 = acc[st][ct][3] + bp[3];
            uint2 pk;
            pk.x = (unsigned)f2bf(v0) | ((unsigned)f2bf(v1) << 16);
            pk.y = (unsigned)f2bf(v2) | ((unsigned)f2bf(v3) << 16);
            *(uint2*)(orow + ct * 16 + kq * 4) = pk;
        }
    }
}

// ---------------- BN stats over transposed bf16 y ---------------------------
template<int C>
__global__ void stats_t(const unsigned short* __restrict__ y, long long rows,
                        float* __restrict__ partials, int nblk)
{
    constexpr int RG = 256 / C;
    const int tid = threadIdx.x;
    const int co = tid % C;
    const int rg = tid / C;
    float s = 0.f, ss = 0.f;
    for (long long r = (long long)blockIdx.x * RG + rg; r < rows; r += (long long)nblk * RG) {
        const float v = bf2f(y[r * C + co]);
        s += v; ss += v * v;
    }
    __shared__ float red[2][256];
    red[0][tid] = s; red[1][tid] = ss;
    __syncthreads();
    if (tid < C) {
        for (int e = 1; e < RG; ++e) { s += red[0][e * C + tid]; ss += red[1][e * C + tid]; }
        partials[((long long)blockIdx.x * C + tid) * 2 + 0] = s;
        partials[((long long)blockIdx.x * C + tid) * 2 + 1] = ss;
    }
}

// BN+ReLU+maxpool4 on transposed y: [b][W][C] -> [b][W/4][C]
template<int C, int W>
__global__ void bn_pool_t(const unsigned short* __restrict__ y, const float* __restrict__ scale,
                          const float* __restrict__ shift, unsigned short* __restrict__ out)
{
    constexpr int WP = W / 4;
    const int total = BSZ * WP * C;
    for (int idx = blockIdx.x * NTHR + threadIdx.x; idx < total; idx += gridDim.x * NTHR) {
        const int c = idx % C;
        const int rest = idx / C;
        const int wp = rest % WP;
        const int b = rest / WP;
        const float sc = scale[c], sh = shift[c];
        const long long base = ((long long)b * W + 4 * wp) * C + c;
        float mx = 0.f;
#pragma unroll
        for (int q = 0; q < 4; ++q)
            mx = fmaxf(mx, fmaf(sc, bf2f(y[base + q * C]), sh));
        out[idx] = f2bf(mx);
    }
}

// BN+ReLU (no pool), elementwise on transposed layout
template<int C, int W>
__global__ void bn_apply_t(const unsigned short* __restrict__ y, const float* __restrict__ scale,
                           const float* __restrict__ shift, unsigned short* __restrict__ out)
{
    const int total = BSZ * W * C;
    for (int idx = blockIdx.x * NTHR + threadIdx.x; idx < total; idx += gridDim.x * NTHR) {
        const int c = idx % C;
        const float v = fmaxf(fmaf(scale[c], bf2f(y[idx]), shift[c]), 0.f);
        out[idx] = f2bf(v);
    }
}

// BN+ReLU + adaptive-avg-pool(5) fused; block per batch. y: [b][128][64] bf16
__global__ void bn_adapool_t(const unsigned short* __restrict__ y, const float* __restrict__ scale,
                             const float* __restrict__ shift, float* __restrict__ k)
{
    __shared__ float hb[128][64];
    const int b = blockIdx.x, tid = threadIdx.x;
    const int c = tid & 63;
    const float sc = scale[c], sh = shift[c];
    for (int i = tid; i < 128 * 64; i += 256) {
        const int w = i >> 6;
        hb[w][c] = fmaxf(fmaf(sc, bf2f(y[((long long)b * 128 + w) * 64 + c]), sh), 0.f);
    }
    __syncthreads();
    const int bs[5] = {0, 25, 51, 76, 102};
    const int be[5] = {26, 52, 77, 103, 128};
    for (int o = tid; o < 320; o += 256) {
        const int cc = o & 63, bin = o >> 6;
        float acc = 0.f;
        for (int w = bs[bin]; w < be[bin]; ++w) acc += hb[w][cc];
        k[((long long)b * 64 + cc) * 5 + bin] = acc / (float)(be[bin] - bs[bin]);
    }
}

// center+normalize rows of h^T per (b,c), emit 5 window-sum terms. block per b.
__global__ void srow_t(const unsigned short* __restrict__ h, float* __restrict__ Sv)
{
    __shared__ float hb[128][64];
    __shared__ float red[4][64];
    __shared__ float mrow[64];
    const int b = blockIdx.x, tid = threadIdx.x;
    const int c = tid & 63, grp = tid >> 6;
    for (int i = tid; i < 128 * 64; i += 256) {
        const int w = i >> 6;
        hb[w][c] = bf2f(h[((long long)b * 128 + w) * 64 + c]);
    }
    __syncthreads();
    float s = 0.f;
    for (int w = grp * 32; w < grp * 32 + 32; ++w) s += hb[w][c];
    red[grp][c] = s;
    __syncthreads();
    if (tid < 64) mrow[tid] = (red[0][tid] + red[1][tid] + red[2][tid] + red[3][tid]) / 128.f;
    __syncthreads();
    const float m = mrow[c];
    float q = 0.f;
    for (int w = grp * 32; w < grp * 32 + 32; ++w) { const float d = hb[w][c] - m; q += d * d; }
    red[grp][c] = q;
    __syncthreads();
    if (tid < 64) {
        const float n2 = red[0][tid] + red[1][tid] + red[2][tid] + red[3][tid];
        const float n = fmaxf(sqrtf(n2), 1e-12f);
        const float m0 = mrow[tid];
        const float h0 = (hb[0][tid] - m0) / n, h1 = (hb[1][tid] - m0) / n;
        const float hN1 = (hb[127][tid] - m0) / n, hN2 = (hb[126][tid] - m0) / n;
        float* o = Sv + ((long long)b * 64 + tid) * 5;
        o[0] = -(hN2 + hN1); o[1] = -hN1; o[2] = 0.f; o[3] = -h0; o[4] = -(h0 + h1);
    }
}

__global__ void knorm_kernel(const float* __restrict__ k, float* __restrict__ kn, int nrows)
{
    int i = blockIdx.x * NTHR + threadIdx.x;
    if (i >= nrows) return;
    const float* p = k + (long long)i * 5;
    float m = 0.f;
    for (int t = 0; t < 5; ++t) m += p[t];
    m *= 0.2f;
    float v[5]; float n2 = 0.f;
    for (int t = 0; t < 5; ++t) { v[t] = p[t] - m; n2 += v[t] * v[t]; }
    float n = fmaxf(sqrtf(n2), 1e-12f);
    for (int t = 0; t < 5; ++t) kn[(long long)i * 5 + t] = v[t] / n;
}

__global__ void flatnorm_kernel(const float* __restrict__ k, float* __restrict__ out, int nrows, int D)
{
    int i = blockIdx.x * NTHR + threadIdx.x;
    if (i >= nrows) return;
    const float* p = k + (long long)i * D;
    float n2 = 0.f;
    for (int d = 0; d < D; ++d) n2 += p[d] * p[d];
    float n = fmaxf(sqrtf(n2), 1e-12f);
    float* o = out + (long long)i * D;
    for (int d = 0; d < D; ++d) o[d] = p[d] / n;
}

__global__ void simdot_kernel(const float* __restrict__ A, const float* __restrict__ Bm,
                              float* __restrict__ out, int n, int D, float coef)
{
    int j = blockIdx.x * NTHR + threadIdx.x;
    int i = blockIdx.y;
    if (j >= n) return;
    const float* a = A + (long long)i * D;
    const float* b = Bm + (long long)j * D;
    float acc = 0.f;
    for (int d = 0; d < D; ++d) acc += a[d] * b[d];
    out[(long long)i * n + j] = acc * coef;
}

__global__ void infonce_kernel(const float* __restrict__ sim, int n, float invT,
                               float* __restrict__ loss)
{
    int i = threadIdx.x;
    float lp = 0.f;
    if (i < n) {
        const float* row = sim + (long long)i * n;
        float mx = -INFINITY;
        for (int j = 0; j < n; ++j) mx = fmaxf(mx, row[j] * invT);
        float se = 0.f;
        for (int j = 0; j < n; ++j) se += expf(row[j] * invT - mx);
        float lse = mx + logf(se);
        lp = row[i] * invT - lse;
    }
    __shared__ float red[NTHR];
    red[threadIdx.x] = (i < n) ? lp : 0.f;
    __syncthreads();
    for (int off = NTHR / 2; off > 0; off >>= 1) {
        if ((int)threadIdx.x < off) red[threadIdx.x] += red[threadIdx.x + off];
        __syncthreads();
    }
    if (threadIdx.x == 0) *loss = -red[0] / (float)n;
}

__global__ void final_kernel(const float* __restrict__ l, float* __restrict__ out)
{
    out[0] = 0.5f * (l[0] + l[1]) + 0.5f * l[2];
}

// ---------------------------------------------------------------------------

extern "C" void kernel_launch(void* const* d_in, const int* in_sizes, int n_in,
                              void* d_out, int out_size, void* d_ws, size_t ws_size,
                              hipStream_t stream)
{
    const float* x1  = (const float*)d_in[0];
    const float* x2  = (const float*)d_in[1];
    const float* w1  = (const float*)d_in[2];
    const float* b1  = (const float*)d_in[3];
    const float* g1  = (const float*)d_in[4];
    const float* be1 = (const float*)d_in[5];
    const float* w2  = (const float*)d_in[6];
    const float* b2  = (const float*)d_in[7];
    const float* g2  = (const float*)d_in[8];
    const float* be2 = (const float*)d_in[9];
    const float* w3  = (const float*)d_in[10];
    const float* b3  = (const float*)d_in[11];
    const float* g3  = (const float*)d_in[12];
    const float* be3 = (const float*)d_in[13];
    const float* tw1 = (const float*)d_in[14];
    const float* tb1 = (const float*)d_in[15];
    const float* tg1 = (const float*)d_in[16];
    const float* tbe1= (const float*)d_in[17];
    const float* tw2 = (const float*)d_in[18];
    const float* tb2 = (const float*)d_in[19];
    const float* tg2 = (const float*)d_in[20];
    const float* tbe2= (const float*)d_in[21];
    float* out = (float*)d_out;

    char* ws = (char*)d_ws;
    size_t off = 0;
    auto alloc = [&](size_t bytes) -> void* {
        off = (off + 255) & ~(size_t)255;
        void* p = ws + off;
        off += bytes;
        return p;
    };
    typedef unsigned short u16;
    // bf16 transposed activations
    u16* xT2  = (u16*)alloc((size_t)BSZ * 2048 * 16 * 2);   // stage1 out  16.8MB
    u16* yT2  = (u16*)alloc((size_t)BSZ * 2048 * 32 * 2);   // stage2 y    33.6MB
    u16* s2o  = (u16*)alloc((size_t)BSZ * 512 * 32 * 2);    // stage2 out   8.4MB
    u16* yT3  = (u16*)alloc((size_t)BSZ * 512 * 64 * 2);    // stage3 y    16.8MB
    u16* h1T  = (u16*)alloc((size_t)BSZ * 128 * 64 * 2);    // h1           4.2MB
    u16* h2T  = (u16*)alloc((size_t)BSZ * 128 * 64 * 2);    // h2           4.2MB
    u16* yTt  = (u16*)alloc((size_t)BSZ * 128 * 64 * 2);    // t-head y     4.2MB
    u16* t1o  = (u16*)alloc((size_t)BSZ * 128 * 64 * 2);    // t1 out       4.2MB
    // weight packs
    u16* wp2  = (u16*)alloc((size_t)9 * 1 * 2 * 512 * 2);
    u16* wp3  = (u16*)alloc((size_t)17 * 1 * 4 * 512 * 2);
    u16* wpt1 = (u16*)alloc((size_t)5 * 2 * 4 * 512 * 2);
    u16* wpt2 = (u16*)alloc((size_t)3 * 2 * 4 * 512 * 2);
    // fp32 small
    float* k1   = (float*)alloc((size_t)BSZ * 64 * 5 * 4);
    float* k2   = (float*)alloc((size_t)BSZ * 64 * 5 * 4);
    float* kn1  = (float*)alloc((size_t)BSZ * 64 * 5 * 4);
    float* kn2  = (float*)alloc((size_t)BSZ * 64 * 5 * 4);
    float* a1   = (float*)alloc((size_t)BSZ * 64 * 5 * 4);
    float* a2   = (float*)alloc((size_t)BSZ * 64 * 5 * 4);
    float* S1   = (float*)alloc((size_t)BSZ * 64 * 5 * 4);
    float* S2   = (float*)alloc((size_t)BSZ * 64 * 5 * 4);
    float* simA = (float*)alloc((size_t)BSZ * BSZ * 4);
    float* simB = (float*)alloc((size_t)BSZ * BSZ * 4);
    float* simT = (float*)alloc((size_t)BSZ * BSZ * 4);
    float* partials = (float*)alloc((size_t)8192 * 64 * 2 * 4);
    float* scale = (float*)alloc(64 * 4);
    float* shift = (float*)alloc(64 * 4);
    float* losses = (float*)alloc(4 * 4);

    // ---- weight prepacks (once; shared by both passes) ----
    build_wpack<16, 17, 2, 9, 1, 2><<<ceil_divll(9 * 2 * 512, NTHR), NTHR, 0, stream>>>(w2, wp2);
    build_wpack<32, 17, 1, 17, 1, 4><<<ceil_divll(17 * 4 * 512, NTHR), NTHR, 0, stream>>>(w3, wp3);
    build_wpack<64, 5, 1, 5, 2, 4><<<ceil_divll(5 * 2 * 4 * 512, NTHR), NTHR, 0, stream>>>(tw1, wpt1);
    build_wpack<64, 3, 1, 3, 2, 4><<<ceil_divll(3 * 2 * 4 * 512, NTHR), NTHR, 0, stream>>>(tw2, wpt2);

    auto run_pass = [&](const float* x, u16* hT, float* kout) {
        // stage 1: fp32 conv, stats + apply(transposed bf16 pooled out)
        {
            const int W = 8192, nblk = BSZ * (W / 256);
            conv_fast<1,16,17,8,256,16,1,0><<<nblk, 256, 0, stream>>>(x, w1, b1, nullptr, nullptr, nullptr, partials, W);
            finalize_kernel<16><<<16, NTHR, 0, stream>>>(partials, nblk, 1.f/((float)BSZ*W), g1, be1, scale, shift);
            conv_fast<1,16,17,8,256,16,1,4><<<nblk, 256, 0, stream>>>(x, w1, b1, scale, shift, xT2, nullptr, W);
        }
        // stage 2: MFMA conv (Cin16->Cout32, W=2048)
        {
            conv_mfma<16,32,17,8,2,9,1,2,4><<<BSZ * (2048/256), 256, 0, stream>>>(xT2, wp2, b2, yT2, 2048);
            stats_t<32><<<2048, 256, 0, stream>>>(yT2, (long long)BSZ * 2048, partials, 2048);
            finalize_kernel<32><<<32, NTHR, 0, stream>>>(partials, 2048, 1.f/((float)BSZ*2048), g2, be2, scale, shift);
            bn_pool_t<32, 2048><<<2048, NTHR, 0, stream>>>(yT2, scale, shift, s2o);
        }
        // stage 3: MFMA conv (Cin32->Cout64, W=512)
        {
            conv_mfma<32,64,17,8,1,17,1,4,4><<<BSZ * (512/256), 256, 0, stream>>>(s2o, wp3, b3, yT3, 512);
            stats_t<64><<<1024, 256, 0, stream>>>(yT3, (long long)BSZ * 512, partials, 1024);
            finalize_kernel<64><<<64, NTHR, 0, stream>>>(partials, 1024, 1.f/((float)BSZ*512), g3, be3, scale, shift);
            bn_pool_t<64, 512><<<1024, NTHR, 0, stream>>>(yT3, scale, shift, hT);
        }
        // template stage 1: MFMA conv (64->64, K=5, W=128)
        {
            conv_mfma<64,64,5,2,1,5,2,4,2><<<BSZ, 256, 0, stream>>>(hT, wpt1, tb1, yTt, 128);
            stats_t<64><<<512, 256, 0, stream>>>(yTt, (long long)BSZ * 128, partials, 512);
            finalize_kernel<64><<<64, NTHR, 0, stream>>>(partials, 512, 1.f/((float)BSZ*128), tg1, tbe1, scale, shift);
            bn_apply_t<64, 128><<<1024, NTHR, 0, stream>>>(yTt, scale, shift, t1o);
        }
        // template stage 2: MFMA conv (64->64, K=3, W=128) + fused BN+adapool
        {
            conv_mfma<64,64,3,1,1,3,2,4,2><<<BSZ, 256, 0, stream>>>(t1o, wpt2, tb2, yTt, 128);
            stats_t<64><<<512, 256, 0, stream>>>(yTt, (long long)BSZ * 128, partials, 512);
            finalize_kernel<64><<<64, NTHR, 0, stream>>>(partials, 512, 1.f/((float)BSZ*128), tg2, tbe2, scale, shift);
            bn_adapool_t<<<BSZ, 256, 0, stream>>>(yTt, scale, shift, kout);
        }
    };

    run_pass(x1, h1T, k1);
    run_pass(x2, h2T, k2);

    const int nrows = BSZ * 64;
    knorm_kernel<<<ceil_divll(nrows, NTHR), NTHR, 0, stream>>>(k1, kn1, nrows);
    knorm_kernel<<<ceil_divll(nrows, NTHR), NTHR, 0, stream>>>(k2, kn2, nrows);
    srow_t<<<BSZ, 256, 0, stream>>>(h1T, S1);
    srow_t<<<BSZ, 256, 0, stream>>>(h2T, S2);
    flatnorm_kernel<<<1, NTHR, 0, stream>>>(k1, a1, BSZ, 320);
    flatnorm_kernel<<<1, NTHR, 0, stream>>>(k2, a2, BSZ, 320);

    dim3 sg(1, BSZ);
    simdot_kernel<<<sg, NTHR, 0, stream>>>(kn1, S2, simA, BSZ, 320, 1.f / 128.f);
    simdot_kernel<<<sg, NTHR, 0, stream>>>(kn2, S1, simB, BSZ, 320, 1.f / 128.f);
    simdot_kernel<<<sg, NTHR, 0, stream>>>(a1, a2, simT, BSZ, 320, 1.f);

    infonce_kernel<<<1, NTHR, 0, stream>>>(simA, BSZ, 10.f, losses + 0);
    infonce_kernel<<<1, NTHR, 0, stream>>>(simB, BSZ, 10.f, losses + 1);
    infonce_kernel<<<1, NTHR, 0, stream>>>(simT, BSZ, 10.f, losses + 2);
    final_kernel<<<1, 1, 0, stream>>>(losses, out);
}

// Round 6
// 393.167 us; speedup vs baseline: 68.7144x; 2.6128x over previous
//
#include <hip/hip_runtime.h>
#include <math.h>

// ---------------------------------------------------------------------------
// TCCL model forward. Round 5 (R4 fix: local 'S' shadowed template param):
//  - double-batch (512): x1,x2 run through every stage together; BN stats
//    finalized per half (blocks are batch-major -> contiguous partials)
//  - BN stats fused into conv_mfma epilogue (shfl over n-lanes + LDS across
//    waves) -> stats_t kernels removed
//  - flatnorm: wave-per-row butterfly (was 1 scalar thread/row, 107us x2)
//  - tail fused: one simdot (z=3), one infonce (3 blocks)
// ---------------------------------------------------------------------------

#define BSZ2 512          // combined batch (x1 ++ x2)
#define NTHR 256

typedef __attribute__((ext_vector_type(8))) short bf16x8;
typedef __attribute__((ext_vector_type(4))) float f32x4;

static inline int ceil_divll(long long a, int b) { return (int)((a + b - 1) / b); }

__device__ __forceinline__ unsigned short f2bf(float f) {
    unsigned u = __float_as_uint(f);
    u = (u + 0x7FFFu + ((u >> 16) & 1u)) >> 16;
    return (unsigned short)u;
}
__device__ __forceinline__ float bf2f(unsigned short h) {
    return __uint_as_float(((unsigned)h) << 16);
}

// ---------------- stage 1: fp32 vector conv (Cin=1), double-batch ----------
// MODE 0 = stats partials only; MODE 4 = BN+ReLU+maxpool4 -> bf16 [b][wp][co]
template<int COUT, int K, int PAD, int TILE, int R, int MODE>
__global__ __launch_bounds__(COUT*(TILE/R))
void conv_s1(const float* __restrict__ x1, const float* __restrict__ x2,
             const float* __restrict__ wgt, const float* __restrict__ bias,
             const float* __restrict__ scale, const float* __restrict__ shift,
             unsigned short* __restrict__ out, float* __restrict__ partials, int W)
{
    constexpr int G  = TILE / R;
    constexpr int NT = COUT * G;
    constexpr int XW = TILE + K - 1;
    __shared__ float xs[XW];
    __shared__ float wsm[COUT][K];

    const int tid  = threadIdx.x;
    const int co   = tid / G;
    const int g    = tid % G;
    const int ntile = W / TILE;
    const int b    = blockIdx.x / ntile;
    const int tile = blockIdx.x % ntile;
    const int w0   = tile * TILE;
    const float* xrow = ((b < 256) ? x1 + (long long)b * W : x2 + (long long)(b - 256) * W);

    if (tid < COUT) {
        const float* src = wgt + tid * K;
#pragma unroll
        for (int t = 0; t < K; ++t) wsm[tid][t] = src[t];
    }
    for (int j = tid; j < XW; j += NT) {
        const int xw = w0 - PAD + j;
        xs[j] = (xw >= 0 && xw < W) ? xrow[xw] : 0.f;
    }
    __syncthreads();

    float acc[R];
#pragma unroll
    for (int r = 0; r < R; ++r) acc[r] = 0.f;
    {
        float xr[R + K - 1];
#pragma unroll
        for (int j = 0; j < R + K - 1; ++j) xr[j] = xs[g * R + j];
#pragma unroll
        for (int t = 0; t < K; ++t) {
            const float wv = wsm[co][t];
#pragma unroll
            for (int r = 0; r < R; ++r) acc[r] = fmaf(xr[r + t], wv, acc[r]);
        }
    }

    const float bi = bias[co];
    if (MODE == 0) {
        float s = 0.f, ss = 0.f;
#pragma unroll
        for (int r = 0; r < R; ++r) { const float y = acc[r] + bi; s += y; ss += y * y; }
        __shared__ float red[NT][2];
        red[tid][0] = s; red[tid][1] = ss;
        __syncthreads();
        if (tid < COUT) {
            float a = 0.f, bb = 0.f;
            for (int e = 0; e < G; ++e) { a += red[tid * G + e][0]; bb += red[tid * G + e][1]; }
            partials[((long long)blockIdx.x * COUT + tid) * 2 + 0] = a;
            partials[((long long)blockIdx.x * COUT + tid) * 2 + 1] = bb;
        }
    } else {
        const float sc = scale[(b >> 8) * COUT + co], sh = shift[(b >> 8) * COUT + co];
        const int wp0 = (w0 + g * R) >> 2;
#pragma unroll
        for (int p = 0; p < R / 4; ++p) {
            float mx = 0.f;
#pragma unroll
            for (int q = 0; q < 4; ++q) mx = fmaxf(mx, fmaf(sc, acc[p * 4 + q] + bi, sh));
            out[((long long)b * (W >> 2) + wp0 + p) * COUT + co] = f2bf(mx);
        }
    }
}

// per-channel, per-half finalize. grid (COUT, 2).
template<int COUT>
__global__ void finalize2(const float* __restrict__ partials, int nblk_half, float invN,
                          const float* __restrict__ g, const float* __restrict__ be,
                          float* __restrict__ scale, float* __restrict__ shift)
{
    const int co = blockIdx.x;
    const int half = blockIdx.y;
    const float* P = partials + (size_t)half * nblk_half * COUT * 2;
    float s = 0.f, ss = 0.f;
    for (int i = threadIdx.x; i < nblk_half; i += NTHR) {
        s  += P[((long long)i * COUT + co) * 2 + 0];
        ss += P[((long long)i * COUT + co) * 2 + 1];
    }
    __shared__ float red[NTHR][2];
    red[threadIdx.x][0] = s; red[threadIdx.x][1] = ss;
    __syncthreads();
    for (int off = NTHR / 2; off > 0; off >>= 1) {
        if ((int)threadIdx.x < off) {
            red[threadIdx.x][0] += red[threadIdx.x + off][0];
            red[threadIdx.x][1] += red[threadIdx.x + off][1];
        }
        __syncthreads();
    }
    if (threadIdx.x == 0) {
        const float m = red[0][0] * invN;
        const float v = red[0][1] * invN - m * m;
        const float inv = rsqrtf(v + 1e-5f);
        const float sc = g[co] * inv;
        scale[half * COUT + co] = sc;
        shift[half * COUT + co] = be[co] - sc * m;
    }
}

// ---------------- weight prepack into MFMA A-frag layout --------------------
template<int CIN, int KK, int DT, int NP, int S, int CT>
__global__ void build_wpack(const float* __restrict__ wgt, unsigned short* __restrict__ wp)
{
    const int idx = blockIdx.x * NTHR + threadIdx.x;
    constexpr int TOT = NP * S * CT * 512;
    if (idx >= TOT) return;
    const int j = idx & 7;
    const int l = (idx >> 3) & 63;
    int rest = idx >> 9;
    const int ct = rest % CT; rest /= CT;
    const int s = rest % S;
    const int p = rest / S;
    const int co = ct * 16 + (l & 15);
    const int k = (l >> 4) * 8 + j;
    int ci, t;
    if (DT == 2) { ci = k & (CIN - 1); t = p * 2 + (k >> 4); }
    else         { ci = s * 32 + k;    t = p; }
    float v = (t < KK) ? wgt[((long long)co * CIN + ci) * KK + t] : 0.f;
    wp[idx] = f2bf(v);
}

// ---------------- MFMA conv with fused BN-stats partials --------------------
// xT: [b][W][CIN] bf16.  yT: [b][W][COUT] bf16 (= conv + bias, pre-BN).
template<int CIN, int COUT, int KK, int PAD, int DT, int NP, int S, int CT, int ST>
__global__ __launch_bounds__(256)
void conv_mfma(const unsigned short* __restrict__ xT, const unsigned short* __restrict__ wpack,
               const float* __restrict__ bias, unsigned short* __restrict__ yT,
               float* __restrict__ partials, int W)
{
    constexpr int CHUNK = 4 * ST * 16;
    constexpr int ROWB = CIN * 2 + 16;
    constexpr int ROWS = CHUNK + KK + (DT - 1) + 1;
    constexpr int DPR = CIN / 2;
    __shared__ __align__(16) unsigned char lx[ROWS * ROWB];
    __shared__ float sred[4][CT][4][4];
    __shared__ float ssred[4][CT][4][4];

    const int tid = threadIdx.x;
    const int ntile = W / CHUNK;
    const int b = blockIdx.x / ntile;
    const int tile = blockIdx.x % ntile;
    const int w0 = tile * CHUNK;

    for (int d = tid; d < ROWS * DPR; d += 256) {
        const int row = d / DPR;
        const int col = d % DPR;
        const int gw = w0 - PAD + row;
        unsigned v = 0;
        if (gw >= 0 && gw < W)
            v = *(const unsigned*)(xT + (((long long)b * W + gw) * CIN + col * 2));
        *(unsigned*)(lx + row * ROWB + col * 4) = v;
    }
    __syncthreads();

    const int lane = tid & 63, wave = tid >> 6;
    const int n = lane & 15, kq = lane >> 4;
    int rowbase, cbyte;
    if (DT == 2) { rowbase = wave * ST * 16 + n + (kq >> 1); cbyte = (kq & 1) * 16; }
    else         { rowbase = wave * ST * 16 + n;             cbyte = kq * 16; }

    f32x4 acc[ST][CT];
#pragma unroll
    for (int st = 0; st < ST; ++st)
#pragma unroll
        for (int ct = 0; ct < CT; ++ct) { acc[st][ct][0]=0.f; acc[st][ct][1]=0.f; acc[st][ct][2]=0.f; acc[st][ct][3]=0.f; }

#pragma unroll
    for (int p = 0; p < NP; ++p) {
#pragma unroll
        for (int s = 0; s < S; ++s) {
            bf16x8 a[CT];
#pragma unroll
            for (int ct = 0; ct < CT; ++ct)
                a[ct] = *(const bf16x8*)(wpack + (((long long)(p * S + s) * CT + ct) * 64 + lane) * 8);
#pragma unroll
            for (int st = 0; st < ST; ++st) {
                const int r = rowbase + st * 16 + p * DT;
                const bf16x8 bf = *(const bf16x8*)(lx + r * ROWB + cbyte + s * 64);
#pragma unroll
                for (int ct = 0; ct < CT; ++ct)
                    acc[st][ct] = __builtin_amdgcn_mfma_f32_16x16x32_bf16(a[ct], bf, acc[st][ct], 0, 0, 0);
            }
        }
    }

    // epilogue: bias add, bf16 store, per-channel stats partials
    float s_[CT][4], ss_[CT][4];
#pragma unroll
    for (int ct = 0; ct < CT; ++ct)
#pragma unroll
        for (int e = 0; e < 4; ++e) { s_[ct][e] = 0.f; ss_[ct][e] = 0.f; }

#pragma unroll
    for (int st = 0; st < ST; ++st) {
        const int w = w0 + wave * ST * 16 + st * 16 + n;
        unsigned short* orow = yT + ((long long)b * W + w) * COUT;
#pragma unroll
        for (int ct = 0; ct < CT; ++ct) {
            const float* bp = bias + ct * 16 + kq * 4;
            float v[4];
#pragma unroll
            for (int e = 0; e < 4; ++e) {
                v[e] = acc[st][ct][e] + bp[e];
                s_[ct][e] += v[e];
                ss_[ct][e] += v[e] * v[e];
            }
            uint2 pk;
            pk.x = (unsigned)f2bf(v[0]) | ((unsigned)f2bf(v[1]) << 16);
            pk.y = (unsigned)f2bf(v[2]) | ((unsigned)f2bf(v[3]) << 16);
            *(uint2*)(orow + ct * 16 + kq * 4) = pk;
        }
    }
    // reduce over the 16 n-lanes (lane low bits)
#pragma unroll
    for (int m = 1; m < 16; m <<= 1) {
#pragma unroll
        for (int ct = 0; ct < CT; ++ct)
#pragma unroll
            for (int e = 0; e < 4; ++e) {
                s_[ct][e]  += __shfl_xor(s_[ct][e], m, 64);
                ss_[ct][e] += __shfl_xor(ss_[ct][e], m, 64);
            }
    }
    if (n == 0) {
#pragma unroll
        for (int ct = 0; ct < CT; ++ct)
#pragma unroll
            for (int e = 0; e < 4; ++e) {
                sred[wave][ct][kq][e] = s_[ct][e];
                ssred[wave][ct][kq][e] = ss_[ct][e];
            }
    }
    __syncthreads();
    if (tid < COUT) {
        const int ct = tid >> 4, q = (tid >> 2) & 3, e = tid & 3;
        float sumv = 0.f, sumsq = 0.f;
#pragma unroll
        for (int wv = 0; wv < 4; ++wv) { sumv += sred[wv][ct][q][e]; sumsq += ssred[wv][ct][q][e]; }
        partials[((long long)blockIdx.x * COUT + tid) * 2 + 0] = sumv;
        partials[((long long)blockIdx.x * COUT + tid) * 2 + 1] = sumsq;
    }
}

// BN+ReLU+maxpool4 on transposed y: [b][W][C] -> [b][W/4][C]  (batch 512)
template<int C, int W>
__global__ void bn_pool_t(const unsigned short* __restrict__ y, const float* __restrict__ scale,
                          const float* __restrict__ shift, unsigned short* __restrict__ out)
{
    constexpr int WP = W / 4;
    const int total = BSZ2 * WP * C;
    for (int idx = blockIdx.x * NTHR + threadIdx.x; idx < total; idx += gridDim.x * NTHR) {
        const int c = idx % C;
        const int rest = idx / C;
        const int wp = rest % WP;
        const int b = rest / WP;
        const float sc = scale[(b >> 8) * C + c], sh = shift[(b >> 8) * C + c];
        const long long base = ((long long)b * W + 4 * wp) * C + c;
        float mx = 0.f;
#pragma unroll
        for (int q = 0; q < 4; ++q)
            mx = fmaxf(mx, fmaf(sc, bf2f(y[base + q * C]), sh));
        out[idx] = f2bf(mx);
    }
}

// BN+ReLU (no pool) elementwise  (batch 512)
template<int C, int W>
__global__ void bn_apply_t(const unsigned short* __restrict__ y, const float* __restrict__ scale,
                           const float* __restrict__ shift, unsigned short* __restrict__ out)
{
    const int total = BSZ2 * W * C;
    for (int idx = blockIdx.x * NTHR + threadIdx.x; idx < total; idx += gridDim.x * NTHR) {
        const int c = idx % C;
        const int b = idx / (W * C);
        const float v = fmaxf(fmaf(scale[(b >> 8) * C + c], bf2f(y[idx]), shift[(b >> 8) * C + c]), 0.f);
        out[idx] = f2bf(v);
    }
}

// BN+ReLU + adaptive-avg-pool(5); block per batch row. y: [b][128][64] bf16
__global__ void bn_adapool_t(const unsigned short* __restrict__ y, const float* __restrict__ scale,
                             const float* __restrict__ shift, float* __restrict__ kk)
{
    __shared__ float hb[128][64];
    const int b = blockIdx.x, tid = threadIdx.x;
    const int c = tid & 63;
    const float sc = scale[(b >> 8) * 64 + c], sh = shift[(b >> 8) * 64 + c];
    for (int i = tid; i < 128 * 64; i += 256) {
        const int w = i >> 6;
        hb[w][c] = fmaxf(fmaf(sc, bf2f(y[((long long)b * 128 + w) * 64 + c]), sh), 0.f);
    }
    __syncthreads();
    const int bs[5] = {0, 25, 51, 76, 102};
    const int be[5] = {26, 52, 77, 103, 128};
    for (int o = tid; o < 320; o += 256) {
        const int cc = o & 63, bin = o >> 6;
        float acc = 0.f;
        for (int w = bs[bin]; w < be[bin]; ++w) acc += hb[w][cc];
        kk[((long long)b * 64 + cc) * 5 + bin] = acc / (float)(be[bin] - bs[bin]);
    }
}

// center+normalize rows of h^T per (b,c), emit 5 window-sum terms. block per b.
__global__ void srow_t(const unsigned short* __restrict__ h, float* __restrict__ Sv)
{
    __shared__ float hb[128][64];
    __shared__ float red[4][64];
    __shared__ float mrow[64];
    const int b = blockIdx.x, tid = threadIdx.x;
    const int c = tid & 63, grp = tid >> 6;
    for (int i = tid; i < 128 * 64; i += 256) {
        const int w = i >> 6;
        hb[w][c] = bf2f(h[((long long)b * 128 + w) * 64 + c]);
    }
    __syncthreads();
    float s = 0.f;
    for (int w = grp * 32; w < grp * 32 + 32; ++w) s += hb[w][c];
    red[grp][c] = s;
    __syncthreads();
    if (tid < 64) mrow[tid] = (red[0][tid] + red[1][tid] + red[2][tid] + red[3][tid]) / 128.f;
    __syncthreads();
    const float m = mrow[c];
    float q = 0.f;
    for (int w = grp * 32; w < grp * 32 + 32; ++w) { const float d = hb[w][c] - m; q += d * d; }
    red[grp][c] = q;
    __syncthreads();
    if (tid < 64) {
        const float n2 = red[0][tid] + red[1][tid] + red[2][tid] + red[3][tid];
        const float n = fmaxf(sqrtf(n2), 1e-12f);
        const float m0 = mrow[tid];
        const float h0 = (hb[0][tid] - m0) / n, h1 = (hb[1][tid] - m0) / n;
        const float hN1 = (hb[127][tid] - m0) / n, hN2 = (hb[126][tid] - m0) / n;
        float* o = Sv + ((long long)b * 64 + tid) * 5;
        o[0] = -(hN2 + hN1); o[1] = -hN1; o[2] = 0.f; o[3] = -h0; o[4] = -(h0 + h1);
    }
}

__global__ void knorm_kernel(const float* __restrict__ k, float* __restrict__ kn, int nrows)
{
    int i = blockIdx.x * NTHR + threadIdx.x;
    if (i >= nrows) return;
    const float* p = k + (long long)i * 5;
    float m = 0.f;
    for (int t = 0; t < 5; ++t) m += p[t];
    m *= 0.2f;
    float v[5]; float n2 = 0.f;
    for (int t = 0; t < 5; ++t) { v[t] = p[t] - m; n2 += v[t] * v[t]; }
    float n = fmaxf(sqrtf(n2), 1e-12f);
    for (int t = 0; t < 5; ++t) kn[(long long)i * 5 + t] = v[t] / n;
}

// l2-normalize 512 rows of 320; one wave per row.
__global__ void flatnorm2(const float* __restrict__ k, float* __restrict__ out)
{
    const int wave = threadIdx.x >> 6, lane = threadIdx.x & 63;
    const int row = blockIdx.x * 4 + wave;
    const float* p = k + (long long)row * 320;
    float n2 = 0.f;
    for (int d = lane; d < 320; d += 64) n2 += p[d] * p[d];
#pragma unroll
    for (int m = 1; m < 64; m <<= 1) n2 += __shfl_xor(n2, m, 64);
    const float n = fmaxf(sqrtf(n2), 1e-12f);
    float* o = out + (long long)row * 320;
    for (int d = lane; d < 320; d += 64) o[d] = p[d] / n;
}

// fused 3-way similarity. grid (1, 256, 3), block 256.
__global__ void simdot3(const float* __restrict__ kn, const float* __restrict__ Sv,
                        const float* __restrict__ ab, float* __restrict__ sim)
{
    const int j = threadIdx.x;
    const int i = blockIdx.y;
    const int z = blockIdx.z;
    const float* a;
    const float* b;
    float coef;
    if (z == 0)      { a = kn + (long long)i * 320;         b = Sv + (long long)(256 + j) * 320; coef = 1.f / 128.f; }
    else if (z == 1) { a = kn + (long long)(256 + i) * 320; b = Sv + (long long)j * 320;         coef = 1.f / 128.f; }
    else             { a = ab + (long long)i * 320;         b = ab + (long long)(256 + j) * 320; coef = 1.f; }
    float acc = 0.f;
    for (int d = 0; d < 320; ++d) acc += a[d] * b[d];
    sim[(long long)z * 65536 + i * 256 + j] = acc * coef;
}

// grid 3 blocks; block 256. losses[z] = infonce(sim_z * 10)
__global__ void infonce3(const float* __restrict__ sims, float* __restrict__ losses)
{
    const int z = blockIdx.x;
    const float* sim = sims + (long long)z * 65536;
    const int i = threadIdx.x;
    const float* row = sim + (long long)i * 256;
    float mx = -INFINITY;
    for (int j = 0; j < 256; ++j) mx = fmaxf(mx, row[j] * 10.f);
    float se = 0.f;
    for (int j = 0; j < 256; ++j) se += expf(row[j] * 10.f - mx);
    const float lp = row[i] * 10.f - (mx + logf(se));
    __shared__ float red[NTHR];
    red[threadIdx.x] = lp;
    __syncthreads();
    for (int off = NTHR / 2; off > 0; off >>= 1) {
        if ((int)threadIdx.x < off) red[threadIdx.x] += red[threadIdx.x + off];
        __syncthreads();
    }
    if (threadIdx.x == 0) losses[z] = -red[0] / 256.f;
}

__global__ void final_kernel(const float* __restrict__ l, float* __restrict__ out)
{
    out[0] = 0.5f * (l[0] + l[1]) + 0.5f * l[2];
}

// ---------------------------------------------------------------------------

extern "C" void kernel_launch(void* const* d_in, const int* in_sizes, int n_in,
                              void* d_out, int out_size, void* d_ws, size_t ws_size,
                              hipStream_t stream)
{
    const float* x1  = (const float*)d_in[0];
    const float* x2  = (const float*)d_in[1];
    const float* w1  = (const float*)d_in[2];
    const float* b1  = (const float*)d_in[3];
    const float* g1  = (const float*)d_in[4];
    const float* be1 = (const float*)d_in[5];
    const float* w2  = (const float*)d_in[6];
    const float* b2  = (const float*)d_in[7];
    const float* g2  = (const float*)d_in[8];
    const float* be2 = (const float*)d_in[9];
    const float* w3  = (const float*)d_in[10];
    const float* b3  = (const float*)d_in[11];
    const float* g3  = (const float*)d_in[12];
    const float* be3 = (const float*)d_in[13];
    const float* tw1 = (const float*)d_in[14];
    const float* tb1 = (const float*)d_in[15];
    const float* tg1 = (const float*)d_in[16];
    const float* tbe1= (const float*)d_in[17];
    const float* tw2 = (const float*)d_in[18];
    const float* tb2 = (const float*)d_in[19];
    const float* tg2 = (const float*)d_in[20];
    const float* tbe2= (const float*)d_in[21];
    float* out = (float*)d_out;

    char* ws = (char*)d_ws;
    size_t off = 0;
    auto alloc = [&](size_t bytes) -> void* {
        off = (off + 255) & ~(size_t)255;
        void* p = ws + off;
        off += bytes;
        return p;
    };
    typedef unsigned short u16;
    // activations (batch 512, bf16 transposed [b][w][c])
    u16* xT2  = (u16*)alloc((size_t)BSZ2 * 2048 * 16 * 2);  // stage1 out   33.6MB
    u16* bigY = (u16*)alloc((size_t)BSZ2 * 2048 * 32 * 2);  // y scratch    67MB (reused)
    u16* s2o  = (u16*)alloc((size_t)BSZ2 * 512 * 32 * 2);   // stage2 out   16.8MB
    u16* hT   = (u16*)alloc((size_t)BSZ2 * 128 * 64 * 2);   // h (both)      8.4MB
    u16* t1o  = (u16*)alloc((size_t)BSZ2 * 128 * 64 * 2);   // t1 out        8.4MB
    // weight packs
    u16* wp2  = (u16*)alloc((size_t)9 * 1 * 2 * 512 * 2);
    u16* wp3  = (u16*)alloc((size_t)17 * 1 * 4 * 512 * 2);
    u16* wpt1 = (u16*)alloc((size_t)5 * 2 * 4 * 512 * 2);
    u16* wpt2 = (u16*)alloc((size_t)3 * 2 * 4 * 512 * 2);
    // fp32 small
    float* kk   = (float*)alloc((size_t)BSZ2 * 320 * 4);    // k (both halves)
    float* kn   = (float*)alloc((size_t)BSZ2 * 320 * 4);
    float* ab   = (float*)alloc((size_t)BSZ2 * 320 * 4);
    float* Sv   = (float*)alloc((size_t)BSZ2 * 320 * 4);
    float* sims = (float*)alloc((size_t)3 * 256 * 256 * 4);
    float* partials = (float*)alloc((size_t)16384 * 16 * 2 * 4);  // 2 MB (max: stage1)
    float* scale = (float*)alloc(2 * 64 * 4);
    float* shift = (float*)alloc(2 * 64 * 4);
    float* losses = (float*)alloc(4 * 4);

    // weight prepacks
    build_wpack<16, 17, 2, 9, 1, 2><<<ceil_divll(9 * 2 * 512, NTHR), NTHR, 0, stream>>>(w2, wp2);
    build_wpack<32, 17, 1, 17, 1, 4><<<ceil_divll(17 * 4 * 512, NTHR), NTHR, 0, stream>>>(w3, wp3);
    build_wpack<64, 5, 1, 5, 2, 4><<<ceil_divll(5 * 2 * 4 * 512, NTHR), NTHR, 0, stream>>>(tw1, wpt1);
    build_wpack<64, 3, 1, 3, 2, 4><<<ceil_divll(3 * 2 * 4 * 512, NTHR), NTHR, 0, stream>>>(tw2, wpt2);

    // ---- stage 1: fp32 conv, stats -> finalize(2 halves) -> apply ----
    {
        const int W = 8192, ntile = W / 256, nblk = BSZ2 * ntile;
        conv_s1<16,17,8,256,16,0><<<nblk, 256, 0, stream>>>(x1, x2, w1, b1, nullptr, nullptr, nullptr, partials, W);
        dim3 fg(16, 2);
        finalize2<16><<<fg, NTHR, 0, stream>>>(partials, 256 * ntile, 1.f/((float)256 * W), g1, be1, scale, shift);
        conv_s1<16,17,8,256,16,4><<<nblk, 256, 0, stream>>>(x1, x2, w1, b1, scale, shift, xT2, nullptr, W);
    }
    // ---- stage 2: MFMA conv (16->32, W=2048) ----
    {
        const int ntile = 2048 / 256;
        conv_mfma<16,32,17,8,2,9,1,2,4><<<BSZ2 * ntile, 256, 0, stream>>>(xT2, wp2, b2, bigY, partials, 2048);
        dim3 fg(32, 2);
        finalize2<32><<<fg, NTHR, 0, stream>>>(partials, 256 * ntile, 1.f/((float)256 * 2048), g2, be2, scale, shift);
        bn_pool_t<32, 2048><<<2048, NTHR, 0, stream>>>(bigY, scale, shift, s2o);
    }
    // ---- stage 3: MFMA conv (32->64, W=512) ----
    {
        const int ntile = 512 / 256;
        conv_mfma<32,64,17,8,1,17,1,4,4><<<BSZ2 * ntile, 256, 0, stream>>>(s2o, wp3, b3, bigY, partials, 512);
        dim3 fg(64, 2);
        finalize2<64><<<fg, NTHR, 0, stream>>>(partials, 256 * ntile, 1.f/((float)256 * 512), g3, be3, scale, shift);
        bn_pool_t<64, 512><<<2048, NTHR, 0, stream>>>(bigY, scale, shift, hT);
    }
    // ---- template stage 1: MFMA conv (64->64, K=5, W=128) ----
    {
        conv_mfma<64,64,5,2,1,5,2,4,2><<<BSZ2, 256, 0, stream>>>(hT, wpt1, tb1, bigY, partials, 128);
        dim3 fg(64, 2);
        finalize2<64><<<fg, NTHR, 0, stream>>>(partials, 256, 1.f/((float)256 * 128), tg1, tbe1, scale, shift);
        bn_apply_t<64, 128><<<2048, NTHR, 0, stream>>>(bigY, scale, shift, t1o);
    }
    // ---- template stage 2: MFMA conv (64->64, K=3, W=128) + BN+adapool ----
    {
        conv_mfma<64,64,3,1,1,3,2,4,2><<<BSZ2, 256, 0, stream>>>(t1o, wpt2, tb2, bigY, partials, 128);
        dim3 fg(64, 2);
        finalize2<64><<<fg, NTHR, 0, stream>>>(partials, 256, 1.f/((float)256 * 128), tg2, tbe2, scale, shift);
        bn_adapool_t<<<BSZ2, 256, 0, stream>>>(bigY, scale, shift, kk);
    }

    // ---- tail ----
    knorm_kernel<<<BSZ2 * 64 / NTHR, NTHR, 0, stream>>>(kk, kn, BSZ2 * 64);
    srow_t<<<BSZ2, 256, 0, stream>>>(hT, Sv);
    flatnorm2<<<BSZ2 / 4, 256, 0, stream>>>(kk, ab);
    dim3 sg(1, 256, 3);
    simdot3<<<sg, NTHR, 0, stream>>>(kn, Sv, ab, sims);
    infonce3<<<3, NTHR, 0, stream>>>(sims, losses);
    final_kernel<<<1, 1, 0, stream>>>(losses, out);
}

// Round 7
// 292.408 us; speedup vs baseline: 92.3924x; 1.3446x over previous
//
#include <hip/hip_runtime.h>
#include <math.h>

// ---------------------------------------------------------------------------
// TCCL model forward. Round 6:
//  - conv_s1 thread remap co=tid&15 (was co=tid/16): sliding-window LDS read
//    now 4 broadcast groups/wave -> 2-way bank conflict (free) instead of
//    8-way (R5: 3.9e7 conflict-cycles = ~68% of dispatch)
//  - BN apply kernels vectorized (dword / uint2 channel packing)
//  - dispatch merges: 1 prepack kernel, knorm+flatnorm merged, simdot+infonce
//    fused (block computes row + in-block LSE)
// ---------------------------------------------------------------------------

#define BSZ2 512          // combined batch (x1 ++ x2)
#define NTHR 256

typedef __attribute__((ext_vector_type(8))) short bf16x8;
typedef __attribute__((ext_vector_type(4))) float f32x4;

static inline int ceil_divll(long long a, int b) { return (int)((a + b - 1) / b); }

__device__ __forceinline__ unsigned short f2bf(float f) {
    unsigned u = __float_as_uint(f);
    u = (u + 0x7FFFu + ((u >> 16) & 1u)) >> 16;
    return (unsigned short)u;
}
__device__ __forceinline__ float bf2f(unsigned short h) {
    return __uint_as_float(((unsigned)h) << 16);
}
__device__ __forceinline__ float bflo(unsigned u) { return __uint_as_float(u << 16); }
__device__ __forceinline__ float bfhi(unsigned u) { return __uint_as_float(u & 0xFFFF0000u); }

// ---------------- stage 1: fp32 vector conv (Cin=1), double-batch ----------
// co = tid & 15, g = tid >> 4  (4 g-groups/wave -> broadcast LDS reads)
// MODE 0 = stats partials only; MODE 4 = BN+ReLU+maxpool4 -> bf16 [b][wp][co]
template<int COUT, int K, int PAD, int TILE, int R, int MODE>
__global__ __launch_bounds__(COUT*(TILE/R))
void conv_s1(const float* __restrict__ x1, const float* __restrict__ x2,
             const float* __restrict__ wgt, const float* __restrict__ bias,
             const float* __restrict__ scale, const float* __restrict__ shift,
             unsigned short* __restrict__ out, float* __restrict__ partials, int W)
{
    constexpr int G  = TILE / R;           // 16
    constexpr int NT = COUT * G;           // 256
    constexpr int XW = TILE + K - 1;       // 272
    __shared__ float xs[XW];
    __shared__ float wsm[COUT * K];
    __shared__ float redS[G][COUT];
    __shared__ float redQ[G][COUT];

    const int tid  = threadIdx.x;
    const int co   = tid & (COUT - 1);
    const int g    = tid >> 4;
    const int ntile = W / TILE;
    const int b    = blockIdx.x / ntile;
    const int tile = blockIdx.x % ntile;
    const int w0   = tile * TILE;
    const float* xrow = ((b < 256) ? x1 + (long long)b * W : x2 + (long long)(b - 256) * W);

    for (int i = tid; i < COUT * K; i += NT) wsm[i] = wgt[i];
    for (int j = tid; j < XW; j += NT) {
        const int xw = w0 - PAD + j;
        xs[j] = (xw >= 0 && xw < W) ? xrow[xw] : 0.f;
    }
    __syncthreads();

    float acc[R];
#pragma unroll
    for (int r = 0; r < R; ++r) acc[r] = 0.f;
    {
        float xr[R + K - 1];
#pragma unroll
        for (int j = 0; j < R + K - 1; ++j) xr[j] = xs[g * R + j];
#pragma unroll
        for (int t = 0; t < K; ++t) {
            const float wv = wsm[co * K + t];
#pragma unroll
            for (int r = 0; r < R; ++r) acc[r] = fmaf(xr[r + t], wv, acc[r]);
        }
    }

    const float bi = bias[co];
    if (MODE == 0) {
        float s = 0.f, ss = 0.f;
#pragma unroll
        for (int r = 0; r < R; ++r) { const float y = acc[r] + bi; s += y; ss += y * y; }
        redS[g][co] = s; redQ[g][co] = ss;
        __syncthreads();
        if (tid < COUT) {
            float a = 0.f, bb = 0.f;
#pragma unroll
            for (int e = 0; e < G; ++e) { a += redS[e][tid]; bb += redQ[e][tid]; }
            partials[((long long)blockIdx.x * COUT + tid) * 2 + 0] = a;
            partials[((long long)blockIdx.x * COUT + tid) * 2 + 1] = bb;
        }
    } else {
        const float sc = scale[(b >> 8) * COUT + co], sh = shift[(b >> 8) * COUT + co];
        const int wp0 = (w0 >> 2) + g * (R / 4);
#pragma unroll
        for (int p = 0; p < R / 4; ++p) {
            float mx = 0.f;
#pragma unroll
            for (int q = 0; q < 4; ++q) mx = fmaxf(mx, fmaf(sc, acc[p * 4 + q] + bi, sh));
            out[((long long)b * (W >> 2) + wp0 + p) * COUT + co] = f2bf(mx);
        }
    }
}

// per-channel, per-half finalize. grid (COUT, 2).
template<int COUT>
__global__ void finalize2(const float* __restrict__ partials, int nblk_half, float invN,
                          const float* __restrict__ g, const float* __restrict__ be,
                          float* __restrict__ scale, float* __restrict__ shift)
{
    const int co = blockIdx.x;
    const int half = blockIdx.y;
    const float* P = partials + (size_t)half * nblk_half * COUT * 2;
    float s = 0.f, ss = 0.f;
    for (int i = threadIdx.x; i < nblk_half; i += NTHR) {
        s  += P[((long long)i * COUT + co) * 2 + 0];
        ss += P[((long long)i * COUT + co) * 2 + 1];
    }
    __shared__ float red[NTHR][2];
    red[threadIdx.x][0] = s; red[threadIdx.x][1] = ss;
    __syncthreads();
    for (int off = NTHR / 2; off > 0; off >>= 1) {
        if ((int)threadIdx.x < off) {
            red[threadIdx.x][0] += red[threadIdx.x + off][0];
            red[threadIdx.x][1] += red[threadIdx.x + off][1];
        }
        __syncthreads();
    }
    if (threadIdx.x == 0) {
        const float m = red[0][0] * invN;
        const float v = red[0][1] * invN - m * m;
        const float inv = rsqrtf(v + 1e-5f);
        const float sc = g[co] * inv;
        scale[half * COUT + co] = sc;
        shift[half * COUT + co] = be[co] - sc * m;
    }
}

// ---------------- weight prepack (all 4 packs, one launch) ------------------
template<int CIN, int KK, int DT, int NP, int S, int CT>
__device__ __forceinline__ void pack_one(int idx, const float* __restrict__ wgt,
                                         unsigned short* __restrict__ wp)
{
    const int j = idx & 7;
    const int l = (idx >> 3) & 63;
    int rest = idx >> 9;
    const int ct = rest % CT; rest /= CT;
    const int s = rest % S;
    const int p = rest / S;
    const int co = ct * 16 + (l & 15);
    const int k = (l >> 4) * 8 + j;
    int ci, t;
    if (DT == 2) { ci = k & (CIN - 1); t = p * 2 + (k >> 4); }
    else         { ci = s * 32 + k;    t = p; }
    float v = (t < KK) ? wgt[((long long)co * CIN + ci) * KK + t] : 0.f;
    wp[idx] = f2bf(v);
}

__global__ void build_all_wpacks(const float* __restrict__ w2, const float* __restrict__ w3,
                                 const float* __restrict__ tw1, const float* __restrict__ tw2,
                                 unsigned short* __restrict__ wp2, unsigned short* __restrict__ wp3,
                                 unsigned short* __restrict__ wpt1, unsigned short* __restrict__ wpt2)
{
    const int idx = blockIdx.x * NTHR + threadIdx.x;
    const int n2 = 9 * 1 * 2 * 512;       // 9216
    const int n3 = 17 * 1 * 4 * 512;      // 34816
    const int nt1 = 5 * 2 * 4 * 512;      // 20480
    const int nt2 = 3 * 2 * 4 * 512;      // 12288
    if (idx < n2) pack_one<16, 17, 2, 9, 1, 2>(idx, w2, wp2);
    else if (idx < n2 + n3) pack_one<32, 17, 1, 17, 1, 4>(idx - n2, w3, wp3);
    else if (idx < n2 + n3 + nt1) pack_one<64, 5, 1, 5, 2, 4>(idx - n2 - n3, tw1, wpt1);
    else if (idx < n2 + n3 + nt1 + nt2) pack_one<64, 3, 1, 3, 2, 4>(idx - n2 - n3 - nt1, tw2, wpt2);
}

// ---------------- MFMA conv with fused BN-stats partials --------------------
template<int CIN, int COUT, int KK, int PAD, int DT, int NP, int S, int CT, int ST>
__global__ __launch_bounds__(256)
void conv_mfma(const unsigned short* __restrict__ xT, const unsigned short* __restrict__ wpack,
               const float* __restrict__ bias, unsigned short* __restrict__ yT,
               float* __restrict__ partials, int W)
{
    constexpr int CHUNK = 4 * ST * 16;
    constexpr int ROWB = CIN * 2 + 16;
    constexpr int ROWS = CHUNK + KK + (DT - 1) + 1;
    constexpr int DPR = CIN / 2;
    __shared__ __align__(16) unsigned char lx[ROWS * ROWB];
    __shared__ float sred[4][CT][4][4];
    __shared__ float ssred[4][CT][4][4];

    const int tid = threadIdx.x;
    const int ntile = W / CHUNK;
    const int b = blockIdx.x / ntile;
    const int tile = blockIdx.x % ntile;
    const int w0 = tile * CHUNK;

    for (int d = tid; d < ROWS * DPR; d += 256) {
        const int row = d / DPR;
        const int col = d % DPR;
        const int gw = w0 - PAD + row;
        unsigned v = 0;
        if (gw >= 0 && gw < W)
            v = *(const unsigned*)(xT + (((long long)b * W + gw) * CIN + col * 2));
        *(unsigned*)(lx + row * ROWB + col * 4) = v;
    }
    __syncthreads();

    const int lane = tid & 63, wave = tid >> 6;
    const int n = lane & 15, kq = lane >> 4;
    int rowbase, cbyte;
    if (DT == 2) { rowbase = wave * ST * 16 + n + (kq >> 1); cbyte = (kq & 1) * 16; }
    else         { rowbase = wave * ST * 16 + n;             cbyte = kq * 16; }

    f32x4 acc[ST][CT];
#pragma unroll
    for (int st = 0; st < ST; ++st)
#pragma unroll
        for (int ct = 0; ct < CT; ++ct) { acc[st][ct][0]=0.f; acc[st][ct][1]=0.f; acc[st][ct][2]=0.f; acc[st][ct][3]=0.f; }

#pragma unroll
    for (int p = 0; p < NP; ++p) {
#pragma unroll
        for (int s = 0; s < S; ++s) {
            bf16x8 a[CT];
#pragma unroll
            for (int ct = 0; ct < CT; ++ct)
                a[ct] = *(const bf16x8*)(wpack + (((long long)(p * S + s) * CT + ct) * 64 + lane) * 8);
#pragma unroll
            for (int st = 0; st < ST; ++st) {
                const int r = rowbase + st * 16 + p * DT;
                const bf16x8 bf = *(const bf16x8*)(lx + r * ROWB + cbyte + s * 64);
#pragma unroll
                for (int ct = 0; ct < CT; ++ct)
                    acc[st][ct] = __builtin_amdgcn_mfma_f32_16x16x32_bf16(a[ct], bf, acc[st][ct], 0, 0, 0);
            }
        }
    }

    float s_[CT][4], ss_[CT][4];
#pragma unroll
    for (int ct = 0; ct < CT; ++ct)
#pragma unroll
        for (int e = 0; e < 4; ++e) { s_[ct][e] = 0.f; ss_[ct][e] = 0.f; }

#pragma unroll
    for (int st = 0; st < ST; ++st) {
        const int w = w0 + wave * ST * 16 + st * 16 + n;
        unsigned short* orow = yT + ((long long)b * W + w) * COUT;
#pragma unroll
        for (int ct = 0; ct < CT; ++ct) {
            const float* bp = bias + ct * 16 + kq * 4;
            float v[4];
#pragma unroll
            for (int e = 0; e < 4; ++e) {
                v[e] = acc[st][ct][e] + bp[e];
                s_[ct][e] += v[e];
                ss_[ct][e] += v[e] * v[e];
            }
            uint2 pk;
            pk.x = (unsigned)f2bf(v[0]) | ((unsigned)f2bf(v[1]) << 16);
            pk.y = (unsigned)f2bf(v[2]) | ((unsigned)f2bf(v[3]) << 16);
            *(uint2*)(orow + ct * 16 + kq * 4) = pk;
        }
    }
#pragma unroll
    for (int m = 1; m < 16; m <<= 1) {
#pragma unroll
        for (int ct = 0; ct < CT; ++ct)
#pragma unroll
            for (int e = 0; e < 4; ++e) {
                s_[ct][e]  += __shfl_xor(s_[ct][e], m, 64);
                ss_[ct][e] += __shfl_xor(ss_[ct][e], m, 64);
            }
    }
    if (n == 0) {
#pragma unroll
        for (int ct = 0; ct < CT; ++ct)
#pragma unroll
            for (int e = 0; e < 4; ++e) {
                sred[wave][ct][kq][e] = s_[ct][e];
                ssred[wave][ct][kq][e] = ss_[ct][e];
            }
    }
    __syncthreads();
    if (tid < COUT) {
        const int ct = tid >> 4, q = (tid >> 2) & 3, e = tid & 3;
        float sumv = 0.f, sumsq = 0.f;
#pragma unroll
        for (int wv = 0; wv < 4; ++wv) { sumv += sred[wv][ct][q][e]; sumsq += ssred[wv][ct][q][e]; }
        partials[((long long)blockIdx.x * COUT + tid) * 2 + 0] = sumv;
        partials[((long long)blockIdx.x * COUT + tid) * 2 + 1] = sumsq;
    }
}

// BN+ReLU+maxpool4 on transposed y, channel-pair vectorized.
template<int C, int W>
__global__ void bn_pool_t(const unsigned short* __restrict__ y, const float* __restrict__ scale,
                          const float* __restrict__ shift, unsigned short* __restrict__ out)
{
    constexpr int WP = W / 4;
    constexpr int C2 = C / 2;
    const int total = BSZ2 * WP * C2;
    const unsigned* yd = (const unsigned*)y;
    unsigned* od = (unsigned*)out;
    for (int idx = blockIdx.x * NTHR + threadIdx.x; idx < total; idx += gridDim.x * NTHR) {
        const int c2 = idx % C2;
        const int rest = idx / C2;
        const int wp = rest % WP;
        const int b = rest / WP;
        const int c0 = 2 * c2;
        const float sc0 = scale[(b >> 8) * C + c0], sh0 = shift[(b >> 8) * C + c0];
        const float sc1 = scale[(b >> 8) * C + c0 + 1], sh1 = shift[(b >> 8) * C + c0 + 1];
        const long long base = (((long long)b * W + 4 * wp) * C) / 2 + c2;
        float m0 = 0.f, m1 = 0.f;
#pragma unroll
        for (int q = 0; q < 4; ++q) {
            const unsigned v = yd[base + (long long)q * C2];
            m0 = fmaxf(m0, fmaf(sc0, bflo(v), sh0));
            m1 = fmaxf(m1, fmaf(sc1, bfhi(v) , sh1));
        }
        od[idx] = (unsigned)f2bf(m0) | ((unsigned)f2bf(m1) << 16);
    }
}

// BN+ReLU (no pool), 4-channel vectorized.
template<int C, int W>
__global__ void bn_apply_t(const unsigned short* __restrict__ y, const float* __restrict__ scale,
                           const float* __restrict__ shift, unsigned short* __restrict__ out)
{
    constexpr int C4 = C / 4;
    const int total = BSZ2 * W * C4;
    const uint2* yd = (const uint2*)y;
    uint2* od = (uint2*)out;
    for (int idx = blockIdx.x * NTHR + threadIdx.x; idx < total; idx += gridDim.x * NTHR) {
        const int c4 = idx % C4;
        const int b = idx / (W * C4);
        const int c0 = 4 * c4;
        const float* scp = scale + (b >> 8) * C + c0;
        const float* shp = shift + (b >> 8) * C + c0;
        const uint2 v = yd[idx];
        const float r0 = fmaxf(fmaf(scp[0], bflo(v.x), shp[0]), 0.f);
        const float r1 = fmaxf(fmaf(scp[1], bfhi(v.x), shp[1]), 0.f);
        const float r2 = fmaxf(fmaf(scp[2], bflo(v.y), shp[2]), 0.f);
        const float r3 = fmaxf(fmaf(scp[3], bfhi(v.y), shp[3]), 0.f);
        uint2 o;
        o.x = (unsigned)f2bf(r0) | ((unsigned)f2bf(r1) << 16);
        o.y = (unsigned)f2bf(r2) | ((unsigned)f2bf(r3) << 16);
        od[idx] = o;
    }
}

// BN+ReLU + adaptive-avg-pool(5); block per batch row. y: [b][128][64] bf16
__global__ void bn_adapool_t(const unsigned short* __restrict__ y, const float* __restrict__ scale,
                             const float* __restrict__ shift, float* __restrict__ kk)
{
    __shared__ float hb[128][64];
    const int b = blockIdx.x, tid = threadIdx.x;
    const uint2* yd = (const uint2*)(y + (long long)b * 128 * 64);
    for (int i = tid; i < 128 * 16; i += 256) {
        const int w = i >> 4, c4 = (i & 15) * 4;
        const float* scp = scale + (b >> 8) * 64 + c4;
        const float* shp = shift + (b >> 8) * 64 + c4;
        const uint2 v = yd[i];
        hb[w][c4 + 0] = fmaxf(fmaf(scp[0], bflo(v.x), shp[0]), 0.f);
        hb[w][c4 + 1] = fmaxf(fmaf(scp[1], bfhi(v.x), shp[1]), 0.f);
        hb[w][c4 + 2] = fmaxf(fmaf(scp[2], bflo(v.y), shp[2]), 0.f);
        hb[w][c4 + 3] = fmaxf(fmaf(scp[3], bfhi(v.y), shp[3]), 0.f);
    }
    __syncthreads();
    const int bs[5] = {0, 25, 51, 76, 102};
    const int be[5] = {26, 52, 77, 103, 128};
    for (int o = tid; o < 320; o += 256) {
        const int cc = o & 63, bin = o >> 6;
        float acc = 0.f;
        for (int w = bs[bin]; w < be[bin]; ++w) acc += hb[w][cc];
        kk[((long long)b * 64 + cc) * 5 + bin] = acc / (float)(be[bin] - bs[bin]);
    }
}

// center+normalize rows of h^T per (b,c), emit 5 window-sum terms. block per b.
__global__ void srow_t(const unsigned short* __restrict__ h, float* __restrict__ Sv)
{
    __shared__ float hb[128][64];
    __shared__ float red[4][64];
    __shared__ float mrow[64];
    const int b = blockIdx.x, tid = threadIdx.x;
    const int c = tid & 63, grp = tid >> 6;
    const uint2* yd = (const uint2*)(h + (long long)b * 128 * 64);
    for (int i = tid; i < 128 * 16; i += 256) {
        const int w = i >> 4, c4 = (i & 15) * 4;
        const uint2 v = yd[i];
        hb[w][c4 + 0] = bflo(v.x);
        hb[w][c4 + 1] = bfhi(v.x);
        hb[w][c4 + 2] = bflo(v.y);
        hb[w][c4 + 3] = bfhi(v.y);
    }
    __syncthreads();
    float s = 0.f;
    for (int w = grp * 32; w < grp * 32 + 32; ++w) s += hb[w][c];
    red[grp][c] = s;
    __syncthreads();
    if (tid < 64) mrow[tid] = (red[0][tid] + red[1][tid] + red[2][tid] + red[3][tid]) / 128.f;
    __syncthreads();
    const float m = mrow[c];
    float q = 0.f;
    for (int w = grp * 32; w < grp * 32 + 32; ++w) { const float d = hb[w][c] - m; q += d * d; }
    red[grp][c] = q;
    __syncthreads();
    if (tid < 64) {
        const float n2 = red[0][tid] + red[1][tid] + red[2][tid] + red[3][tid];
        const float n = fmaxf(sqrtf(n2), 1e-12f);
        const float m0 = mrow[tid];
        const float h0 = (hb[0][tid] - m0) / n, h1 = (hb[1][tid] - m0) / n;
        const float hN1 = (hb[127][tid] - m0) / n, hN2 = (hb[126][tid] - m0) / n;
        float* o = Sv + ((long long)b * 64 + tid) * 5;
        o[0] = -(hN2 + hN1); o[1] = -hN1; o[2] = 0.f; o[3] = -h0; o[4] = -(h0 + h1);
    }
}

// merged: blocks [0,128) = flatnorm (wave-per-row), [128,256) = knorm
__global__ void norm_both(const float* __restrict__ kk, float* __restrict__ kn,
                          float* __restrict__ ab)
{
    if (blockIdx.x < 128) {
        const int wave = threadIdx.x >> 6, lane = threadIdx.x & 63;
        const int row = blockIdx.x * 4 + wave;
        const float* p = kk + (long long)row * 320;
        float n2 = 0.f;
        for (int d = lane; d < 320; d += 64) n2 += p[d] * p[d];
#pragma unroll
        for (int m = 1; m < 64; m <<= 1) n2 += __shfl_xor(n2, m, 64);
        const float n = fmaxf(sqrtf(n2), 1e-12f);
        float* o = ab + (long long)row * 320;
        for (int d = lane; d < 320; d += 64) o[d] = p[d] / n;
    } else {
        const int i = (blockIdx.x - 128) * NTHR + threadIdx.x;   // < 32768
        const float* p = kk + (long long)i * 5;
        float m = 0.f;
        for (int t = 0; t < 5; ++t) m += p[t];
        m *= 0.2f;
        float v[5]; float n2 = 0.f;
        for (int t = 0; t < 5; ++t) { v[t] = p[t] - m; n2 += v[t] * v[t]; }
        float n = fmaxf(sqrtf(n2), 1e-12f);
        for (int t = 0; t < 5; ++t) kn[(long long)i * 5 + t] = v[t] / n;
    }
}

// fused similarity + per-row log-softmax diag. grid (256, 3), block 256.
// lp[z*256+i] = sim_z[i][i]*10 - lse(sim_z[i][:]*10)
__global__ void simdot_nce(const float* __restrict__ kn, const float* __restrict__ Sv,
                           const float* __restrict__ ab, float* __restrict__ lp)
{
    const int j = threadIdx.x;
    const int i = blockIdx.x;
    const int z = blockIdx.y;
    const float* a;
    const float* b;
    float coef;
    if (z == 0)      { a = kn + (long long)i * 320;         b = Sv + (long long)(256 + j) * 320; coef = 10.f / 128.f; }
    else if (z == 1) { a = kn + (long long)(256 + i) * 320; b = Sv + (long long)j * 320;         coef = 10.f / 128.f; }
    else             { a = ab + (long long)i * 320;         b = ab + (long long)(256 + j) * 320; coef = 10.f; }
    float acc = 0.f;
    for (int d = 0; d < 320; ++d) acc += a[d] * b[d];
    const float v = acc * coef;

    __shared__ float red[NTHR];
    __shared__ float sdiag;
    if (j == i) sdiag = v;
    red[j] = v;
    __syncthreads();
    for (int off = NTHR / 2; off > 0; off >>= 1) {
        if (j < off) red[j] = fmaxf(red[j], red[j + off]);
        __syncthreads();
    }
    const float mx = red[0];
    __syncthreads();
    red[j] = expf(v - mx);
    __syncthreads();
    for (int off = NTHR / 2; off > 0; off >>= 1) {
        if (j < off) red[j] += red[j + off];
        __syncthreads();
    }
    if (j == 0) lp[z * 256 + i] = sdiag - (mx + logf(red[0]));
}

// reduce lp -> final loss scalar
__global__ void final3(const float* __restrict__ lp, float* __restrict__ out)
{
    __shared__ float red[NTHR];
    const int tid = threadIdx.x;
    float l[3];
    for (int z = 0; z < 3; ++z) {
        red[tid] = lp[z * 256 + tid];
        __syncthreads();
        for (int off = NTHR / 2; off > 0; off >>= 1) {
            if (tid < off) red[tid] += red[tid + off];
            __syncthreads();
        }
        l[z] = red[0];
        __syncthreads();
    }
    if (tid == 0)
        out[0] = 0.5f * (-l[0] / 256.f - l[1] / 256.f) + 0.5f * (-l[2] / 256.f);
}

// ---------------------------------------------------------------------------

extern "C" void kernel_launch(void* const* d_in, const int* in_sizes, int n_in,
                              void* d_out, int out_size, void* d_ws, size_t ws_size,
                              hipStream_t stream)
{
    const float* x1  = (const float*)d_in[0];
    const float* x2  = (const float*)d_in[1];
    const float* w1  = (const float*)d_in[2];
    const float* b1  = (const float*)d_in[3];
    const float* g1  = (const float*)d_in[4];
    const float* be1 = (const float*)d_in[5];
    const float* w2  = (const float*)d_in[6];
    const float* b2  = (const float*)d_in[7];
    const float* g2  = (const float*)d_in[8];
    const float* be2 = (const float*)d_in[9];
    const float* w3  = (const float*)d_in[10];
    const float* b3  = (const float*)d_in[11];
    const float* g3  = (const float*)d_in[12];
    const float* be3 = (const float*)d_in[13];
    const float* tw1 = (const float*)d_in[14];
    const float* tb1 = (const float*)d_in[15];
    const float* tg1 = (const float*)d_in[16];
    const float* tbe1= (const float*)d_in[17];
    const float* tw2 = (const float*)d_in[18];
    const float* tb2 = (const float*)d_in[19];
    const float* tg2 = (const float*)d_in[20];
    const float* tbe2= (const float*)d_in[21];
    float* out = (float*)d_out;

    char* ws = (char*)d_ws;
    size_t off = 0;
    auto alloc = [&](size_t bytes) -> void* {
        off = (off + 255) & ~(size_t)255;
        void* p = ws + off;
        off += bytes;
        return p;
    };
    typedef unsigned short u16;
    u16* xT2  = (u16*)alloc((size_t)BSZ2 * 2048 * 16 * 2);  // stage1 out   33.6MB
    u16* bigY = (u16*)alloc((size_t)BSZ2 * 2048 * 32 * 2);  // y scratch    67MB (reused)
    u16* s2o  = (u16*)alloc((size_t)BSZ2 * 512 * 32 * 2);   // stage2 out   16.8MB
    u16* hT   = (u16*)alloc((size_t)BSZ2 * 128 * 64 * 2);   // h (both)      8.4MB
    u16* t1o  = (u16*)alloc((size_t)BSZ2 * 128 * 64 * 2);   // t1 out        8.4MB
    u16* wp2  = (u16*)alloc((size_t)9 * 1 * 2 * 512 * 2);
    u16* wp3  = (u16*)alloc((size_t)17 * 1 * 4 * 512 * 2);
    u16* wpt1 = (u16*)alloc((size_t)5 * 2 * 4 * 512 * 2);
    u16* wpt2 = (u16*)alloc((size_t)3 * 2 * 4 * 512 * 2);
    float* kk   = (float*)alloc((size_t)BSZ2 * 320 * 4);
    float* kn   = (float*)alloc((size_t)BSZ2 * 320 * 4);
    float* ab   = (float*)alloc((size_t)BSZ2 * 320 * 4);
    float* Sv   = (float*)alloc((size_t)BSZ2 * 320 * 4);
    float* lp   = (float*)alloc((size_t)3 * 256 * 4);
    float* partials = (float*)alloc((size_t)16384 * 16 * 2 * 4);  // 2 MB
    float* scale = (float*)alloc(2 * 64 * 4);
    float* shift = (float*)alloc(2 * 64 * 4);

    // all weight prepacks, one launch (76800 elements)
    build_all_wpacks<<<300, NTHR, 0, stream>>>(w2, w3, tw1, tw2, wp2, wp3, wpt1, wpt2);

    // ---- stage 1: fp32 conv, stats -> finalize(2 halves) -> apply ----
    {
        const int W = 8192, ntile = W / 256, nblk = BSZ2 * ntile;
        conv_s1<16,17,8,256,16,0><<<nblk, 256, 0, stream>>>(x1, x2, w1, b1, nullptr, nullptr, nullptr, partials, W);
        dim3 fg(16, 2);
        finalize2<16><<<fg, NTHR, 0, stream>>>(partials, 256 * ntile, 1.f/((float)256 * W), g1, be1, scale, shift);
        conv_s1<16,17,8,256,16,4><<<nblk, 256, 0, stream>>>(x1, x2, w1, b1, scale, shift, xT2, nullptr, W);
    }
    // ---- stage 2: MFMA conv (16->32, W=2048) ----
    {
        const int ntile = 2048 / 256;
        conv_mfma<16,32,17,8,2,9,1,2,4><<<BSZ2 * ntile, 256, 0, stream>>>(xT2, wp2, b2, bigY, partials, 2048);
        dim3 fg(32, 2);
        finalize2<32><<<fg, NTHR, 0, stream>>>(partials, 256 * ntile, 1.f/((float)256 * 2048), g2, be2, scale, shift);
        bn_pool_t<32, 2048><<<2048, NTHR, 0, stream>>>(bigY, scale, shift, s2o);
    }
    // ---- stage 3: MFMA conv (32->64, W=512) ----
    {
        const int ntile = 512 / 256;
        conv_mfma<32,64,17,8,1,17,1,4,4><<<BSZ2 * ntile, 256, 0, stream>>>(s2o, wp3, b3, bigY, partials, 512);
        dim3 fg(64, 2);
        finalize2<64><<<fg, NTHR, 0, stream>>>(partials, 256 * ntile, 1.f/((float)256 * 512), g3, be3, scale, shift);
        bn_pool_t<64, 512><<<2048, NTHR, 0, stream>>>(bigY, scale, shift, hT);
    }
    // ---- template stage 1: MFMA conv (64->64, K=5, W=128) ----
    {
        conv_mfma<64,64,5,2,1,5,2,4,2><<<BSZ2, 256, 0, stream>>>(hT, wpt1, tb1, bigY, partials, 128);
        dim3 fg(64, 2);
        finalize2<64><<<fg, NTHR, 0, stream>>>(partials, 256, 1.f/((float)256 * 128), tg1, tbe1, scale, shift);
        bn_apply_t<64, 128><<<2048, NTHR, 0, stream>>>(bigY, scale, shift, t1o);
    }
    // ---- template stage 2: MFMA conv (64->64, K=3, W=128) + BN+adapool ----
    {
        conv_mfma<64,64,3,1,1,3,2,4,2><<<BSZ2, 256, 0, stream>>>(t1o, wpt2, tb2, bigY, partials, 128);
        dim3 fg(64, 2);
        finalize2<64><<<fg, NTHR, 0, stream>>>(partials, 256, 1.f/((float)256 * 128), tg2, tbe2, scale, shift);
        bn_adapool_t<<<BSZ2, 256, 0, stream>>>(bigY, scale, shift, kk);
    }

    // ---- tail ----
    srow_t<<<BSZ2, 256, 0, stream>>>(hT, Sv);
    norm_both<<<256, NTHR, 0, stream>>>(kk, kn, ab);
    dim3 sg(256, 3);
    simdot_nce<<<sg, NTHR, 0, stream>>>(kn, Sv, ab, lp);
    final3<<<1, NTHR, 0, stream>>>(lp, out);
}